// Round 18
// baseline (7000.291 us; speedup 1.0000x reference)
//
#include <hip/hip_runtime.h>

// RNNEncModel: embed -> MLP(relu x2) -> 2x bidirectional tanh-RNN -> final states [4,64,1024] f32.
// B=64 T=512 E=512 H=1024 V=32000.
// Round-18: R17 all-PRE structure + ONE atomic counter per (dir,bg,layer) sync group instead of
// a 64-flag vector. Poller waits ctr >= 64*s (single-line broadcast load, was a 64-line gather);
// publisher last-man does atomic_add(ctr,1) after h-store drain. Barrier is provably correct:
// ctr = sum(publishes) <= 64*max_step, so ctr >= 64*s implies ALL blocks published step s-1.
// ws>=256MB: all-PRE path; else R14 fused path (flags). All-asm VMEM discipline kept (R16 fix).

typedef _Float16 f16;
typedef _Float16 f16x8 __attribute__((ext_vector_type(8)));
typedef _Float16 f16x4 __attribute__((ext_vector_type(4)));
typedef float f32x4 __attribute__((ext_vector_type(4)));

static const size_t MB_ = 1024ull * 1024ull;
// ---- fused fallback layout (R14, 196MB) ----
static const size_t OFF_X0    = 0;
static const size_t OFF_X1    = 64 * MB_;
static const size_t OFF_EMB   = OFF_X1;
static const size_t OFF_MLP1  = 96 * MB_;
static const size_t OFF_H     = 192 * MB_;
static const size_t OFF_FLAGS = 192 * MB_ + 512 * 1024;
static const size_t OFF_BIAS  = 192 * MB_ + 576 * 1024;
static const size_t OFF_W1C   = 193 * MB_;
static const size_t OFF_W2C   = 194 * MB_;
static const size_t WS_NEED   = 196 * MB_;
// ---- all-PRE layout (256MB) ----
static const size_t Q_X0     = 0;
static const size_t Q_EMB    = 64 * MB_;
static const size_t Q_MLP1   = 96 * MB_;
static const size_t Q_W1C    = 160 * MB_;
static const size_t Q_W2C    = 161 * MB_;
static const size_t Q_PRE0D0 = 64 * MB_;
static const size_t Q_PRE0D1 = 128 * MB_;
static const size_t Q_HB0    = 192 * MB_;
static const size_t Q_CT0    = 192 * MB_ + 512 * 1024;  // [4 groups][16] u32 (64B padded)
static const size_t Q_BIAS0  = 192 * MB_ + 544 * 1024;
static const size_t Q_PRE1D0 = 0;
static const size_t Q_PRE1D1 = 192 * MB_;
static const size_t Q_HB1    = 64 * MB_;
static const size_t Q_CT1    = 64 * MB_ + 512 * 1024;
static const size_t Q_BIAS1  = 64 * MB_ + 544 * 1024;
static const size_t WS_NEED2 = 256 * MB_;

__device__ __forceinline__ void gld16(const void* g, void* l) {
#if __has_builtin(__builtin_amdgcn_global_load_lds)
  __builtin_amdgcn_global_load_lds((const __attribute__((address_space(1))) void*)g,
                                   (__attribute__((address_space(3))) void*)l, 16, 0, 0);
#else
  *(f16x8*)l = *(const f16x8*)g;
#endif
}

// fast tanh: tanh(|x|) = 1 - 2/(exp2(2*log2e*|x|)+1); hw exp + rcp, abs err ~1e-6 << f16 rounding.
__device__ __forceinline__ float tanh_fast(float x) {
  float ax = __builtin_fabsf(x);
  float e = __builtin_amdgcn_exp2f(ax * 2.8853900817779268f);
  float r = 1.0f - 2.0f * __builtin_amdgcn_rcpf(e + 1.0f);
  return __builtin_copysignf(r, x);
}

// ---------------- utility kernels ----------------

__global__ void zero_k(unsigned int* __restrict__ p, int n) {
  int i = blockIdx.x * blockDim.x + threadIdx.x;
  if (i < n) p[i] = 0u;
}

__global__ void cvt_k(const float* __restrict__ in, f16* __restrict__ out, int n4) {
  int i = blockIdx.x * blockDim.x + threadIdx.x;
  int stride = gridDim.x * blockDim.x;
  for (; i < n4; i += stride) {
    float4 v = ((const float4*)in)[i];
    f16x4 o = {(f16)v.x, (f16)v.y, (f16)v.z, (f16)v.w};
    ((f16x4*)out)[i] = o;
  }
}

__global__ void bias_k(const float* __restrict__ a, const float* __restrict__ b, float* __restrict__ o) {
  int i = blockIdx.x * blockDim.x + threadIdx.x;
  if (i < 4096) o[i] = a[i] + b[i];
}

// embedding gather + f16 convert; padding_idx=0 -> zero row
__global__ void embed_k(const int* __restrict__ src, const float* __restrict__ tab, f16* __restrict__ out) {
  int m = blockIdx.x;
  int tid = threadIdx.x;
  int tok = src[m];
  f16x4 o = {(f16)0.f, (f16)0.f, (f16)0.f, (f16)0.f};
  if (tok != 0) {
    float4 v = *(const float4*)(tab + (size_t)tok * 512 + tid * 4);
    o[0] = (f16)v.x; o[1] = (f16)v.y; o[2] = (f16)v.z; o[3] = (f16)v.w;
  }
  *(f16x4*)(out + (size_t)m * 512 + tid * 4) = o;
}

// ---------------- GEMM: C[M,N] = A[M,K(lda)] * Bw[N,K]^T (B f16) ----------------
template <int EPI>
__global__ __launch_bounds__(256) void gemm_f16(
    const f16* __restrict__ A, int lda, const f16* __restrict__ Bw,
    f16* __restrict__ out, const float* __restrict__ bias, int M, int N, int K) {
  __shared__ alignas(16) f16 As[4096];
  __shared__ alignas(16) f16 Bs[4096];
  const int nt = N >> 7;
  const int bx = blockIdx.x;
  const int tm = bx / nt, tn = bx - tm * nt;
  const int tid = threadIdx.x;
  const int l = tid & 63, w = tid >> 6;
  const int wr = w >> 1, wc = w & 1;
  const int srow = (w << 4) + (l >> 2);
  const int scol = (l & 3) << 3;
  const f16* Ab = A + (size_t)(tm * 128 + srow) * lda + scol;
  const f16* Bb = Bw + (size_t)(tn * 128 + srow) * K + scol;
  f32x4 acc[4][4];
#pragma unroll
  for (int i = 0; i < 4; i++)
#pragma unroll
    for (int j = 0; j < 4; j++) acc[i][j] = (f32x4){0.f, 0.f, 0.f, 0.f};
  const int ar = l & 15, ak = (l >> 4) << 3;
  for (int k0 = 0; k0 < K; k0 += 32) {
    gld16(Ab + k0, &As[tid * 8]);
    gld16(Ab + (size_t)64 * lda + k0, &As[tid * 8 + 2048]);
    gld16(Bb + k0, &Bs[tid * 8]);
    gld16(Bb + (size_t)64 * K + k0, &Bs[tid * 8 + 2048]);
    __syncthreads();
    f16x8 av[4], bv[4];
#pragma unroll
    for (int i = 0; i < 4; i++) av[i] = *(const f16x8*)&As[(wr * 64 + i * 16 + ar) * 32 + ak];
#pragma unroll
    for (int j = 0; j < 4; j++) bv[j] = *(const f16x8*)&Bs[(wc * 64 + j * 16 + ar) * 32 + ak];
#pragma unroll
    for (int i = 0; i < 4; i++)
#pragma unroll
      for (int j = 0; j < 4; j++)
        acc[i][j] = __builtin_amdgcn_mfma_f32_16x16x32_f16(av[i], bv[j], acc[i][j], 0, 0, 0);
    __syncthreads();
  }
  const int r0 = (l >> 4) << 2, c0 = l & 15;
#pragma unroll
  for (int i = 0; i < 4; i++) {
#pragma unroll
    for (int j = 0; j < 4; j++) {
      const int col = tn * 128 + wc * 64 + j * 16 + c0;
      const float bc = (EPI & 1) ? bias[col] : 0.f;
#pragma unroll
      for (int r = 0; r < 4; r++) {
        const int row = tm * 128 + wr * 64 + i * 16 + r0 + r;
        float v = acc[i][j][r];
        if (EPI & 1) { v += bc; v = v > 0.f ? v : 0.f; }
        if (EPI & 2) {
          const int b_ = row >> 9, t = row & 511;
          out[((size_t)(t * 64 + b_) << 10) + col] = (f16)v;
        } else {
          out[(size_t)row * N + col] = (f16)v;
        }
      }
    }
  }
}

// ---------------- GEMM with f32 B operand (register-staged f32->f16) ----------------
__global__ __launch_bounds__(256) void gemm_b32(
    const f16* __restrict__ A, int lda, const float* __restrict__ Bw,
    f16* __restrict__ out, int M, int N, int K) {
  __shared__ alignas(16) f16 As[4096];
  __shared__ alignas(16) f16 Bs[4096];
  const int nt = N >> 7;
  const int bx = blockIdx.x;
  const int tm = bx / nt, tn = bx - tm * nt;
  const int tid = threadIdx.x;
  const int l = tid & 63, w = tid >> 6;
  const int wr = w >> 1, wc = w & 1;
  const int srow = (w << 4) + (l >> 2);
  const int scol = (l & 3) << 3;
  const f16* Ab = A + (size_t)(tm * 128 + srow) * lda + scol;
  const int brow = tid >> 1, bcol = (tid & 1) << 4;
  const float* Bb = Bw + (size_t)(tn * 128 + brow) * K + bcol;
  f32x4 acc[4][4];
#pragma unroll
  for (int i = 0; i < 4; i++)
#pragma unroll
    for (int j = 0; j < 4; j++) acc[i][j] = (f32x4){0.f, 0.f, 0.f, 0.f};
  const int ar = l & 15, ak = (l >> 4) << 3;
  for (int k0 = 0; k0 < K; k0 += 32) {
    gld16(Ab + k0, &As[tid * 8]);
    gld16(Ab + (size_t)64 * lda + k0, &As[tid * 8 + 2048]);
    {
      const float* bp = Bb + k0;
      float4 u0 = *(const float4*)(bp + 0), u1 = *(const float4*)(bp + 4);
      float4 u2 = *(const float4*)(bp + 8), u3 = *(const float4*)(bp + 12);
      f16x8 h0 = {(f16)u0.x, (f16)u0.y, (f16)u0.z, (f16)u0.w,
                  (f16)u1.x, (f16)u1.y, (f16)u1.z, (f16)u1.w};
      f16x8 h1 = {(f16)u2.x, (f16)u2.y, (f16)u2.z, (f16)u2.w,
                  (f16)u3.x, (f16)u3.y, (f16)u3.z, (f16)u3.w};
      *(f16x8*)&Bs[brow * 32 + bcol] = h0;
      *(f16x8*)&Bs[brow * 32 + bcol + 8] = h1;
    }
    __syncthreads();
    f16x8 av[4], bv[4];
#pragma unroll
    for (int i = 0; i < 4; i++) av[i] = *(const f16x8*)&As[(wr * 64 + i * 16 + ar) * 32 + ak];
#pragma unroll
    for (int j = 0; j < 4; j++) bv[j] = *(const f16x8*)&Bs[(wc * 64 + j * 16 + ar) * 32 + ak];
#pragma unroll
    for (int i = 0; i < 4; i++)
#pragma unroll
      for (int j = 0; j < 4; j++)
        acc[i][j] = __builtin_amdgcn_mfma_f32_16x16x32_f16(av[i], bv[j], acc[i][j], 0, 0, 0);
    __syncthreads();
  }
  const int r0 = (l >> 4) << 2, c0 = l & 15;
#pragma unroll
  for (int i = 0; i < 4; i++) {
#pragma unroll
    for (int j = 0; j < 4; j++) {
      const int col = tn * 128 + wc * 64 + j * 16 + c0;
#pragma unroll
      for (int r = 0; r < 4; r++) {
        const int row = tm * 128 + wr * 64 + i * 16 + r0 + r;
        out[(size_t)row * N + col] = (f16)acc[i][j][r];
      }
    }
  }
}

// ---------------- GEMM, f32 B, concat-A (A = [A0 | A1], each [M][1024], K=2048) ----------------
__global__ __launch_bounds__(256) void gemm_b32c(
    const f16* __restrict__ A0, const f16* __restrict__ A1, const float* __restrict__ Bw,
    f16* __restrict__ out, int M, int N) {
  constexpr int K = 2048;
  __shared__ alignas(16) f16 As[4096];
  __shared__ alignas(16) f16 Bs[4096];
  const int nt = N >> 7;
  const int bx = blockIdx.x;
  const int tm = bx / nt, tn = bx - tm * nt;
  const int tid = threadIdx.x;
  const int l = tid & 63, w = tid >> 6;
  const int wr = w >> 1, wc = w & 1;
  const int srow = (w << 4) + (l >> 2);
  const int scol = (l & 3) << 3;
  const int brow = tid >> 1, bcol = (tid & 1) << 4;
  const float* Bb = Bw + (size_t)(tn * 128 + brow) * K + bcol;
  f32x4 acc[4][4];
#pragma unroll
  for (int i = 0; i < 4; i++)
#pragma unroll
    for (int j = 0; j < 4; j++) acc[i][j] = (f32x4){0.f, 0.f, 0.f, 0.f};
  const int ar = l & 15, ak = (l >> 4) << 3;
  for (int k0 = 0; k0 < K; k0 += 32) {
    const f16* base = (k0 < 1024) ? A0 : A1;
    const int ko = k0 & 1023;
    const f16* Ab = base + (size_t)(tm * 128 + srow) * 1024 + ko + scol;
    gld16(Ab, &As[tid * 8]);
    gld16(Ab + (size_t)64 * 1024, &As[tid * 8 + 2048]);
    {
      const float* bp = Bb + k0;
      float4 u0 = *(const float4*)(bp + 0), u1 = *(const float4*)(bp + 4);
      float4 u2 = *(const float4*)(bp + 8), u3 = *(const float4*)(bp + 12);
      f16x8 h0 = {(f16)u0.x, (f16)u0.y, (f16)u0.z, (f16)u0.w,
                  (f16)u1.x, (f16)u1.y, (f16)u1.z, (f16)u1.w};
      f16x8 h1 = {(f16)u2.x, (f16)u2.y, (f16)u2.z, (f16)u2.w,
                  (f16)u3.x, (f16)u3.y, (f16)u3.z, (f16)u3.w};
      *(f16x8*)&Bs[brow * 32 + bcol] = h0;
      *(f16x8*)&Bs[brow * 32 + bcol + 8] = h1;
    }
    __syncthreads();
    f16x8 av[4], bv[4];
#pragma unroll
    for (int i = 0; i < 4; i++) av[i] = *(const f16x8*)&As[(wr * 64 + i * 16 + ar) * 32 + ak];
#pragma unroll
    for (int j = 0; j < 4; j++) bv[j] = *(const f16x8*)&Bs[(wc * 64 + j * 16 + ar) * 32 + ak];
#pragma unroll
    for (int i = 0; i < 4; i++)
#pragma unroll
      for (int j = 0; j < 4; j++)
        acc[i][j] = __builtin_amdgcn_mfma_f32_16x16x32_f16(av[i], bv[j], acc[i][j], 0, 0, 0);
    __syncthreads();
  }
  const int r0 = (l >> 4) << 2, c0 = l & 15;
#pragma unroll
  for (int i = 0; i < 4; i++) {
#pragma unroll
    for (int j = 0; j < 4; j++) {
      const int col = tn * 128 + wc * 64 + j * 16 + c0;
#pragma unroll
      for (int r = 0; r < 4; r++) {
        const int row = tm * 128 + wr * 64 + i * 16 + r0 + r;
        out[(size_t)row * N + col] = (f16)acc[i][j][r];
      }
    }
  }
}

// ---------------- fused recurrence (R14 verbatim — fallback only) ----------------
template <int LAYER>
__global__ __launch_bounds__(512, 1) void rnn_scan(
    const f16* __restrict__ X, const float* __restrict__ Wih, const float* __restrict__ Whh,
    const float* __restrict__ bsum, f16* __restrict__ hbuf, unsigned int* __restrict__ flags,
    f16* __restrict__ seqout, float* __restrict__ dout) {
  constexpr int KX = LAYER ? 2048 : 1024;
  constexpr int XSH = LAYER ? 11 : 10;
  constexpr int NKX = KX / 128;
  constexpr int NKH = 8;
  const int bid = blockIdx.x;
  const int g_ = (bid & 7) >> 1;
  const int dir = g_ >> 1, bg = g_ & 1;
  const int cg = ((bid & 1) << 5) | (bid >> 3);
  const int tid = threadIdx.x, l = tid & 63, w = tid >> 6;
  const int mi = w & 1, kq = w >> 1;
  __shared__ alignas(16) f16 Wl[16 * 1024];
  __shared__ alignas(16) f16 Wi[16 * KX];
  __shared__ f32x4 part[2][4][64];
  __shared__ alignas(16) f16 p2[32][16];
  __shared__ unsigned int cnt;
  const int ld = LAYER * 2 + dir;
  if (tid == 0) cnt = 0u;
  for (int ch = tid; ch < 2048; ch += 512) {
    const int n = ch >> 7, k0 = (ch & 127) << 3;
    const float* wp = Whh + (((size_t)(ld * 1024 + cg * 16 + n)) << 10) + k0;
    float4 v0 = *(const float4*)wp, v1 = *(const float4*)(wp + 4);
    f16x8 hv = {(f16)v0.x, (f16)v0.y, (f16)v0.z, (f16)v0.w,
                (f16)v1.x, (f16)v1.y, (f16)v1.z, (f16)v1.w};
    *(f16x8*)&Wl[(n << 10) + (k0 ^ ((n & 7) << 3))] = hv;
  }
  for (int ch = tid; ch < (16 * KX / 8); ch += 512) {
    const int n = ch >> (XSH - 3), k0 = (ch & (KX / 8 - 1)) << 3;
    const float* wp = Wih + ((size_t)(dir * 1024 + cg * 16 + n)) * KX + k0;
    float4 v0 = *(const float4*)wp, v1 = *(const float4*)(wp + 4);
    f16x8 hv = {(f16)v0.x, (f16)v0.y, (f16)v0.z, (f16)v0.w,
                (f16)v1.x, (f16)v1.y, (f16)v1.z, (f16)v1.w};
    *(f16x8*)&Wi[(n << XSH) + (k0 ^ ((n & 7) << 3))] = hv;
  }
  const float bn = bsum[(ld << 10) + cg * 16 + (l & 15)];
  f16* hD = hbuf + ((size_t)dir << 17);
  unsigned int* fl = flags + ((dir * 2 + bg) << 10);
  const int arow = bg * 32 + mi * 16 + (l & 15);
  const int akh = (kq << 8) + ((l >> 4) << 3);
  const int akx = kq * (KX / 4) + ((l >> 4) << 3);
  const int wn = l & 15;
  const int wsw = (wn & 7) << 3;

  f16x8 xv[NKX];
  {
    const int t0 = dir ? 511 : 0;
    const f16* xr = X + (((size_t)(t0 * 64 + arow)) << XSH) + akx;
#pragma unroll
    for (int i = 0; i < NKX; i++)
      asm volatile("global_load_dwordx4 %0, %1, off offset:%2"
                   : "=&v"(xv[i]) : "v"(xr), "i"(64 * i));
  }
  __syncthreads();

  for (int s = 0; s < 512; ++s) {
    const int t = dir ? (511 - s) : s;
    f32x4 acc = {0.f, 0.f, 0.f, 0.f};
    if (s > 0) {
      if (w == 7) {
        const unsigned int tgt = (unsigned int)(LAYER * 512 + s);
        unsigned int* fp = fl + l * 16;
        for (;;) {
          unsigned int f = __hip_atomic_load(fp, __ATOMIC_RELAXED, __HIP_MEMORY_SCOPE_AGENT);
          if (__all((int)(f >= tgt))) break;
        }
      }
      __syncthreads();
      const f16* hrow = hD + (((size_t)(s & 1)) << 16) + (((size_t)arow) << 10) + akh;
      f16x8 hv[NKH];
#pragma unroll
      for (int i = 0; i < NKH; i++)
        asm volatile("global_load_dwordx4 %0, %1, off offset:%2 sc0 sc1"
                     : "=&v"(hv[i]) : "v"(hrow), "i"(64 * i));
      asm volatile("s_waitcnt vmcnt(%0)" :: "i"(NKH) : "memory");
      __builtin_amdgcn_sched_barrier(0);
#pragma unroll
      for (int it = 0; it < NKX; ++it) {
        const int ko = akx + it * 32;
        f16x8 bv = *(const f16x8*)&Wi[(wn << XSH) + (ko ^ wsw)];
        acc = __builtin_amdgcn_mfma_f32_16x16x32_f16(xv[it], bv, acc, 0, 0, 0);
      }
      asm volatile("s_waitcnt vmcnt(0)" ::: "memory");
      __builtin_amdgcn_sched_barrier(0);
#pragma unroll
      for (int it = 0; it < NKH; ++it) {
        const int ko = akh + it * 32;
        f16x8 bv = *(const f16x8*)&Wl[(wn << 10) + (ko ^ wsw)];
        acc = __builtin_amdgcn_mfma_f32_16x16x32_f16(hv[it], bv, acc, 0, 0, 0);
      }
    } else {
      asm volatile("s_waitcnt vmcnt(0)" ::: "memory");
      __builtin_amdgcn_sched_barrier(0);
#pragma unroll
      for (int it = 0; it < NKX; ++it) {
        const int ko = akx + it * 32;
        f16x8 bv = *(const f16x8*)&Wi[(wn << XSH) + (ko ^ wsw)];
        acc = __builtin_amdgcn_mfma_f32_16x16x32_f16(xv[it], bv, acc, 0, 0, 0);
      }
    }
    part[mi][kq][l] = acc;
    __syncthreads();
    if (w < 2) {
      f32x4 sum = part[w][0][l];
      sum += part[w][1][l];
      sum += part[w][2][l];
      sum += part[w][3][l];
#pragma unroll
      for (int r = 0; r < 4; ++r) {
        const int row = ((l >> 4) << 2) + r;
        float v = tanh_fast(sum[r] + bn);
        p2[(w << 4) + row][l & 15] = (f16)v;
        if (s == 511) {
          const int b_ = bg * 32 + (w << 4) + row;
          dout[(((size_t)(ld * 64 + b_)) << 10) + cg * 16 + (l & 15)] = v;
        }
      }
      asm volatile("s_waitcnt lgkmcnt(0)" ::: "memory");
      __builtin_amdgcn_sched_barrier(0);
      if (l < 32) {
        const int rr = (w << 4) + (l >> 1), hf = l & 1;
        f16x8 pv = *(const f16x8*)&p2[rr][hf * 8];
        const int b_ = bg * 32 + rr;
        f16* hp = hD + (((size_t)((s + 1) & 1)) << 16) + (((size_t)b_) << 10) + cg * 16 + hf * 8;
        asm volatile("global_store_dwordx4 %0, %1, off sc0 sc1" :: "v"(hp), "v"(pv) : "memory");
        if (LAYER == 0) {
          f16* sp = seqout + (((size_t)(t * 64 + b_)) << 11) + (dir << 10) + cg * 16 + hf * 8;
          asm volatile("global_store_dwordx4 %0, %1, off" :: "v"(sp), "v"(pv) : "memory");
        }
      }
      asm volatile("s_waitcnt vmcnt(0)" ::: "memory");
      __builtin_amdgcn_sched_barrier(0);
      if (l == 0) {
        unsigned int old = __hip_atomic_fetch_add(&cnt, 1u, __ATOMIC_RELAXED,
                                                  __HIP_MEMORY_SCOPE_WORKGROUP);
        if (old == (unsigned int)(2 * s + 1))
          __hip_atomic_store(&fl[cg * 16], (unsigned int)(LAYER * 512 + s + 1),
                             __ATOMIC_RELAXED, __HIP_MEMORY_SCOPE_AGENT);
      }
    }
    if (s + 1 < 512) {
      const int tn_ = dir ? (511 - (s + 1)) : (s + 1);
      const f16* xr = X + (((size_t)(tn_ * 64 + arow)) << XSH) + akx;
#pragma unroll
      for (int i = 0; i < NKX; i++)
        asm volatile("global_load_dwordx4 %0, %1, off offset:%2"
                     : "=&v"(xv[i]) : "v"(xr), "i"(64 * i));
    }
  }
}

// ---------------- PRE recurrence (counter barrier; all-asm VMEM) ----------------
// Sync: ctr >= 64*s  <=>  all 64 group blocks published step s-1 (since ctr <= 64*max_step).
// LAYER==0: reducers overlay layer-0 output IN PLACE onto the consumed PRE tile.
template <int LAYER>
__global__ __launch_bounds__(512, 1) void rnn_scan_pre(
    f16* __restrict__ PRE0, f16* __restrict__ PRE1,
    const float* __restrict__ Whh, const float* __restrict__ bsum,
    f16* __restrict__ hbuf, unsigned int* __restrict__ ctrs,  // [4 groups][16] u32 padded
    float* __restrict__ dout) {
  constexpr int NKH = 8;
  const int bid = blockIdx.x;
  const int g_ = (bid & 7) >> 1;
  const int dir = g_ >> 1, bg = g_ & 1;
  const int cg = ((bid & 1) << 5) | (bid >> 3);
  const int tid = threadIdx.x, l = tid & 63, w = tid >> 6;
  const int mi = w & 1, kq = w >> 1;
  __shared__ alignas(16) f16 Wl[16 * 1024];
  __shared__ f32x4 part[2][4][64];
  __shared__ alignas(16) f16 p2[32][16];
  __shared__ unsigned int cnt;
  const int ld = LAYER * 2 + dir;
  if (tid == 0) cnt = 0u;
  for (int ch = tid; ch < 2048; ch += 512) {
    const int n = ch >> 7, k0 = (ch & 127) << 3;
    const float* wp = Whh + (((size_t)(ld * 1024 + cg * 16 + n)) << 10) + k0;
    float4 v0 = *(const float4*)wp, v1 = *(const float4*)(wp + 4);
    f16x8 hv = {(f16)v0.x, (f16)v0.y, (f16)v0.z, (f16)v0.w,
                (f16)v1.x, (f16)v1.y, (f16)v1.z, (f16)v1.w};
    *(f16x8*)&Wl[(n << 10) + (k0 ^ ((n & 7) << 3))] = hv;
  }
  const int pcol = cg * 16 + (l & 15);
  const float bn = bsum[(ld << 10) + pcol];
  f16* preD = dir ? PRE1 : PRE0;
  f16* hD = hbuf + ((size_t)dir << 17);
  unsigned int* ctr = ctrs + ((dir * 2 + bg) << 4);  // 64B apart
  const int arow = bg * 32 + mi * 16 + (l & 15);
  const int akh = (kq << 8) + ((l >> 4) << 3);
  const int wn = l & 15;
  const int wsw = (wn & 7) << 3;
  const int prow = bg * 32 + (w << 4) + ((l >> 4) << 2);

  unsigned int pu0 = 0, pu1 = 0, pu2 = 0, pu3 = 0;
  if (w < 2) {
    const int t0 = dir ? 511 : 0;
    const f16* ppA = preD + (((size_t)(t0 * 64 + prow)) << 10) + pcol;
    const f16* ppB = ppA + 2048;
    asm volatile("global_load_ushort %0, %1, off" : "=&v"(pu0) : "v"(ppA));
    asm volatile("global_load_ushort %0, %1, off offset:2048" : "=&v"(pu1) : "v"(ppA));
    asm volatile("global_load_ushort %0, %1, off" : "=&v"(pu2) : "v"(ppB));
    asm volatile("global_load_ushort %0, %1, off offset:2048" : "=&v"(pu3) : "v"(ppB));
  }
  __syncthreads();

  for (int s = 0; s < 512; ++s) {
    const int t = dir ? (511 - s) : s;
    f32x4 acc = {0.f, 0.f, 0.f, 0.f};
    if (s > 0) {
      if (w == 7) {  // single-line broadcast poll
        const unsigned int tgt = (unsigned int)(s << 6);
        for (;;) {
          unsigned int c = __hip_atomic_load(ctr, __ATOMIC_RELAXED, __HIP_MEMORY_SCOPE_AGENT);
          if (c >= tgt) break;
        }
      }
      __syncthreads();
      const f16* hrow = hD + (((size_t)(s & 1)) << 16) + (((size_t)arow) << 10) + akh;
      f16x8 hv[NKH];
#pragma unroll
      for (int i = 0; i < NKH; i++)
        asm volatile("global_load_dwordx4 %0, %1, off offset:%2 sc0 sc1"
                     : "=&v"(hv[i]) : "v"(hrow), "i"(64 * i));
      asm volatile("s_waitcnt vmcnt(0)" ::: "memory");
      __builtin_amdgcn_sched_barrier(0);
#pragma unroll
      for (int it = 0; it < NKH; ++it) {
        const int ko = akh + it * 32;
        f16x8 bv = *(const f16x8*)&Wl[(wn << 10) + (ko ^ wsw)];
        acc = __builtin_amdgcn_mfma_f32_16x16x32_f16(hv[it], bv, acc, 0, 0, 0);
      }
    }
    part[mi][kq][l] = acc;
    __syncthreads();
    if (w < 2) {
      asm volatile("s_waitcnt vmcnt(0)" ::: "memory");  // pre regs ready
      __builtin_amdgcn_sched_barrier(0);
      float pva[4];
      pva[0] = (float)__builtin_bit_cast(f16, (unsigned short)pu0);
      pva[1] = (float)__builtin_bit_cast(f16, (unsigned short)pu1);
      pva[2] = (float)__builtin_bit_cast(f16, (unsigned short)pu2);
      pva[3] = (float)__builtin_bit_cast(f16, (unsigned short)pu3);
      f32x4 sum = part[w][0][l];
      sum += part[w][1][l];
      sum += part[w][2][l];
      sum += part[w][3][l];
#pragma unroll
      for (int r = 0; r < 4; ++r) {
        const int row = ((l >> 4) << 2) + r;
        float v = tanh_fast(sum[r] + pva[r] + bn);
        p2[(w << 4) + row][l & 15] = (f16)v;
        if (s == 511) {
          const int b_ = bg * 32 + (w << 4) + row;
          dout[(((size_t)(ld * 64 + b_)) << 10) + pcol] = v;
        }
      }
      asm volatile("s_waitcnt lgkmcnt(0)" ::: "memory");
      __builtin_amdgcn_sched_barrier(0);
      if (l < 32) {
        const int rr = (w << 4) + (l >> 1), hf = l & 1;
        f16x8 pv = *(const f16x8*)&p2[rr][hf * 8];
        const int b_ = bg * 32 + rr;
        f16* hp = hD + (((size_t)((s + 1) & 1)) << 16) + (((size_t)b_) << 10) + cg * 16 + hf * 8;
        asm volatile("global_store_dwordx4 %0, %1, off sc0 sc1" :: "v"(hp), "v"(pv) : "memory");
        if (LAYER == 0) {
          f16* xp = preD + (((size_t)(t * 64 + b_)) << 10) + cg * 16 + hf * 8;
          asm volatile("global_store_dwordx4 %0, %1, off" :: "v"(xp), "v"(pv) : "memory");
        }
      }
      asm volatile("s_waitcnt vmcnt(0)" ::: "memory");
      __builtin_amdgcn_sched_barrier(0);
      if (l == 0) {  // last reducer publishes: one atomic add to the group counter
        unsigned int old = __hip_atomic_fetch_add(&cnt, 1u, __ATOMIC_RELAXED,
                                                  __HIP_MEMORY_SCOPE_WORKGROUP);
        if (old == (unsigned int)(2 * s + 1))
          __hip_atomic_fetch_add(ctr, 1u, __ATOMIC_RELAXED, __HIP_MEMORY_SCOPE_AGENT);
      }
      if (s + 1 < 512) {  // single asm issue site, after publish
        const int tn_ = dir ? (511 - (s + 1)) : (s + 1);
        const f16* ppA = preD + (((size_t)(tn_ * 64 + prow)) << 10) + pcol;
        const f16* ppB = ppA + 2048;
        asm volatile("global_load_ushort %0, %1, off" : "=&v"(pu0) : "v"(ppA));
        asm volatile("global_load_ushort %0, %1, off offset:2048" : "=&v"(pu1) : "v"(ppA));
        asm volatile("global_load_ushort %0, %1, off" : "=&v"(pu2) : "v"(ppB));
        asm volatile("global_load_ushort %0, %1, off offset:2048" : "=&v"(pu3) : "v"(ppB));
      }
    }
  }
}

// ---------------- launch ----------------

extern "C" void kernel_launch(void* const* d_in, const int* in_sizes, int n_in,
                              void* d_out, int out_size, void* d_ws, size_t ws_size,
                              hipStream_t stream) {
  const int* src    = (const int*)d_in[0];
  const float* emb  = (const float*)d_in[1];
  const float* W1   = (const float*)d_in[2];
  const float* b1   = (const float*)d_in[3];
  const float* W2   = (const float*)d_in[4];
  const float* b2   = (const float*)d_in[5];
  const float* Wih0 = (const float*)d_in[6];
  const float* WihL = (const float*)d_in[7];
  const float* Whh  = (const float*)d_in[8];
  const float* bih  = (const float*)d_in[9];
  const float* bhh  = (const float*)d_in[10];
  float* out = (float*)d_out;
  char* ws = (char*)d_ws;

  if (ws_size < WS_NEED) {  // diagnostic fallback
    zero_k<<<(out_size + 255) / 256, 256, 0, stream>>>((unsigned int*)d_out, out_size);
    return;
  }

  if (ws_size >= WS_NEED2) {
    // ================= all-PRE path (256MB) =================
    f16* X0    = (f16*)(ws + Q_X0);
    f16* EMB   = (f16*)(ws + Q_EMB);
    f16* MLP1  = (f16*)(ws + Q_MLP1);
    f16* W1C   = (f16*)(ws + Q_W1C);
    f16* W2C   = (f16*)(ws + Q_W2C);
    f16* PRE0D0 = (f16*)(ws + Q_PRE0D0);
    f16* PRE0D1 = (f16*)(ws + Q_PRE0D1);
    f16* HB0   = (f16*)(ws + Q_HB0);
    unsigned int* CT0 = (unsigned int*)(ws + Q_CT0);
    float* BIAS0 = (float*)(ws + Q_BIAS0);
    f16* PRE1D0 = (f16*)(ws + Q_PRE1D0);
    f16* PRE1D1 = (f16*)(ws + Q_PRE1D1);
    f16* HB1   = (f16*)(ws + Q_HB1);
    unsigned int* CT1 = (unsigned int*)(ws + Q_CT1);
    float* BIAS1 = (float*)(ws + Q_BIAS1);

    cvt_k<<<256, 256, 0, stream>>>(W1, W1C, 131072);
    cvt_k<<<256, 256, 0, stream>>>(W2, W2C, 262144);

    embed_k<<<32768, 128, 0, stream>>>(src, emb, EMB);
    gemm_f16<1><<<2048, 256, 0, stream>>>(EMB, 512, W1C, MLP1, b1, 32768, 1024, 512);
    gemm_f16<3><<<2048, 256, 0, stream>>>(MLP1, 1024, W2C, X0, b2, 32768, 1024, 1024);

    gemm_b32<<<2048, 256, 0, stream>>>(X0, 1024, Wih0, PRE0D0, 32768, 1024, 1024);
    gemm_b32<<<2048, 256, 0, stream>>>(X0, 1024, Wih0 + (1u << 20), PRE0D1, 32768, 1024, 1024);
    zero_k<<<1, 64, 0, stream>>>(CT0, 64);
    bias_k<<<16, 256, 0, stream>>>(bih, bhh, BIAS0);
    rnn_scan_pre<0><<<256, 512, 0, stream>>>(PRE0D0, PRE0D1, Whh, BIAS0, HB0, CT0, out);

    gemm_b32c<<<2048, 256, 0, stream>>>(PRE0D0, PRE0D1, WihL, PRE1D0, 32768, 1024);
    gemm_b32c<<<2048, 256, 0, stream>>>(PRE0D0, PRE0D1, WihL + (1u << 21), PRE1D1, 32768, 1024);
    zero_k<<<1, 64, 0, stream>>>(CT1, 64);
    bias_k<<<16, 256, 0, stream>>>(bih, bhh, BIAS1);
    rnn_scan_pre<1><<<256, 512, 0, stream>>>(PRE1D0, PRE1D1, Whh, BIAS1, HB1, CT1, out);
    return;
  }

  // ================= fused fallback (R14, 196MB) =================
  f16* X0   = (f16*)(ws + OFF_X0);
  f16* X1   = (f16*)(ws + OFF_X1);
  f16* EMB  = (f16*)(ws + OFF_EMB);
  f16* MLP1 = (f16*)(ws + OFF_MLP1);
  f16* HB   = (f16*)(ws + OFF_H);
  unsigned int* FLAGS = (unsigned int*)(ws + OFF_FLAGS);
  float* BIAS = (float*)(ws + OFF_BIAS);
  f16* W1C  = (f16*)(ws + OFF_W1C);
  f16* W2C  = (f16*)(ws + OFF_W2C);

  cvt_k<<<256, 256, 0, stream>>>(W1, W1C, 131072);
  cvt_k<<<256, 256, 0, stream>>>(W2, W2C, 262144);
  bias_k<<<16, 256, 0, stream>>>(bih, bhh, BIAS);
  zero_k<<<16, 256, 0, stream>>>(FLAGS, 4096);

  embed_k<<<32768, 128, 0, stream>>>(src, emb, EMB);
  gemm_f16<1><<<2048, 256, 0, stream>>>(EMB, 512, W1C, MLP1, b1, 32768, 1024, 512);
  gemm_f16<3><<<2048, 256, 0, stream>>>(MLP1, 1024, W2C, X0, b2, 32768, 1024, 1024);

  rnn_scan<0><<<256, 512, 0, stream>>>(X0, Wih0, Whh, BIAS, HB, FLAGS, X1, out);
  rnn_scan<1><<<256, 512, 0, stream>>>(X1, WihL, Whh, BIAS, HB, FLAGS, nullptr, out);
}

// Round 19
// 4999.158 us; speedup vs baseline: 1.4003x; 1.4003x over previous
//
#include <hip/hip_runtime.h>

// RNNEncModel: embed -> MLP(relu x2) -> 2x bidirectional tanh-RNN -> final states [4,64,1024] f32.
// B=64 T=512 E=512 H=1024 V=32000.
// Round-19: REVERT to R17 (best: 5.00ms). R18's single-counter barrier regressed 40% (hot-line
// atomic/poll contention); padded per-block flags + single poller wave is the proven optimum.
// Structure: all-PRE path (both scans read precomputed input projections; layer-0 output overlaid
// in place on consumed PRE tiles; all-asm VMEM discipline per R16's compiler lesson; XCD swizzle).
// ws>=256MB: all-PRE; ws>=196MB: R14 fused fallback.

typedef _Float16 f16;
typedef _Float16 f16x8 __attribute__((ext_vector_type(8)));
typedef _Float16 f16x4 __attribute__((ext_vector_type(4)));
typedef float f32x4 __attribute__((ext_vector_type(4)));

static const size_t MB_ = 1024ull * 1024ull;
// ---- fused fallback layout (R14, 196MB) ----
static const size_t OFF_X0    = 0;
static const size_t OFF_X1    = 64 * MB_;
static const size_t OFF_EMB   = OFF_X1;
static const size_t OFF_MLP1  = 96 * MB_;
static const size_t OFF_H     = 192 * MB_;
static const size_t OFF_FLAGS = 192 * MB_ + 512 * 1024;
static const size_t OFF_BIAS  = 192 * MB_ + 576 * 1024;
static const size_t OFF_W1C   = 193 * MB_;
static const size_t OFF_W2C   = 194 * MB_;
static const size_t WS_NEED   = 196 * MB_;
// ---- all-PRE layout (256MB) ----
static const size_t Q_X0     = 0;
static const size_t Q_EMB    = 64 * MB_;
static const size_t Q_MLP1   = 96 * MB_;
static const size_t Q_W1C    = 160 * MB_;
static const size_t Q_W2C    = 161 * MB_;
static const size_t Q_PRE0D0 = 64 * MB_;
static const size_t Q_PRE0D1 = 128 * MB_;
static const size_t Q_HB0    = 192 * MB_;
static const size_t Q_FL0    = 192 * MB_ + 512 * 1024;
static const size_t Q_BIAS0  = 192 * MB_ + 544 * 1024;
static const size_t Q_PRE1D0 = 0;
static const size_t Q_PRE1D1 = 192 * MB_;
static const size_t Q_HB1    = 64 * MB_;
static const size_t Q_FL1    = 64 * MB_ + 512 * 1024;
static const size_t Q_BIAS1  = 64 * MB_ + 544 * 1024;
static const size_t WS_NEED2 = 256 * MB_;

__device__ __forceinline__ void gld16(const void* g, void* l) {
#if __has_builtin(__builtin_amdgcn_global_load_lds)
  __builtin_amdgcn_global_load_lds((const __attribute__((address_space(1))) void*)g,
                                   (__attribute__((address_space(3))) void*)l, 16, 0, 0);
#else
  *(f16x8*)l = *(const f16x8*)g;
#endif
}

// fast tanh: tanh(|x|) = 1 - 2/(exp2(2*log2e*|x|)+1); hw exp + rcp, abs err ~1e-6 << f16 rounding.
__device__ __forceinline__ float tanh_fast(float x) {
  float ax = __builtin_fabsf(x);
  float e = __builtin_amdgcn_exp2f(ax * 2.8853900817779268f);
  float r = 1.0f - 2.0f * __builtin_amdgcn_rcpf(e + 1.0f);
  return __builtin_copysignf(r, x);
}

// ---------------- utility kernels ----------------

__global__ void zero_k(unsigned int* __restrict__ p, int n) {
  int i = blockIdx.x * blockDim.x + threadIdx.x;
  if (i < n) p[i] = 0u;
}

__global__ void cvt_k(const float* __restrict__ in, f16* __restrict__ out, int n4) {
  int i = blockIdx.x * blockDim.x + threadIdx.x;
  int stride = gridDim.x * blockDim.x;
  for (; i < n4; i += stride) {
    float4 v = ((const float4*)in)[i];
    f16x4 o = {(f16)v.x, (f16)v.y, (f16)v.z, (f16)v.w};
    ((f16x4*)out)[i] = o;
  }
}

__global__ void bias_k(const float* __restrict__ a, const float* __restrict__ b, float* __restrict__ o) {
  int i = blockIdx.x * blockDim.x + threadIdx.x;
  if (i < 4096) o[i] = a[i] + b[i];
}

// embedding gather + f16 convert; padding_idx=0 -> zero row
__global__ void embed_k(const int* __restrict__ src, const float* __restrict__ tab, f16* __restrict__ out) {
  int m = blockIdx.x;
  int tid = threadIdx.x;
  int tok = src[m];
  f16x4 o = {(f16)0.f, (f16)0.f, (f16)0.f, (f16)0.f};
  if (tok != 0) {
    float4 v = *(const float4*)(tab + (size_t)tok * 512 + tid * 4);
    o[0] = (f16)v.x; o[1] = (f16)v.y; o[2] = (f16)v.z; o[3] = (f16)v.w;
  }
  *(f16x4*)(out + (size_t)m * 512 + tid * 4) = o;
}

// ---------------- GEMM: C[M,N] = A[M,K(lda)] * Bw[N,K]^T (B f16) ----------------
template <int EPI>
__global__ __launch_bounds__(256) void gemm_f16(
    const f16* __restrict__ A, int lda, const f16* __restrict__ Bw,
    f16* __restrict__ out, const float* __restrict__ bias, int M, int N, int K) {
  __shared__ alignas(16) f16 As[4096];
  __shared__ alignas(16) f16 Bs[4096];
  const int nt = N >> 7;
  const int bx = blockIdx.x;
  const int tm = bx / nt, tn = bx - tm * nt;
  const int tid = threadIdx.x;
  const int l = tid & 63, w = tid >> 6;
  const int wr = w >> 1, wc = w & 1;
  const int srow = (w << 4) + (l >> 2);
  const int scol = (l & 3) << 3;
  const f16* Ab = A + (size_t)(tm * 128 + srow) * lda + scol;
  const f16* Bb = Bw + (size_t)(tn * 128 + srow) * K + scol;
  f32x4 acc[4][4];
#pragma unroll
  for (int i = 0; i < 4; i++)
#pragma unroll
    for (int j = 0; j < 4; j++) acc[i][j] = (f32x4){0.f, 0.f, 0.f, 0.f};
  const int ar = l & 15, ak = (l >> 4) << 3;
  for (int k0 = 0; k0 < K; k0 += 32) {
    gld16(Ab + k0, &As[tid * 8]);
    gld16(Ab + (size_t)64 * lda + k0, &As[tid * 8 + 2048]);
    gld16(Bb + k0, &Bs[tid * 8]);
    gld16(Bb + (size_t)64 * K + k0, &Bs[tid * 8 + 2048]);
    __syncthreads();
    f16x8 av[4], bv[4];
#pragma unroll
    for (int i = 0; i < 4; i++) av[i] = *(const f16x8*)&As[(wr * 64 + i * 16 + ar) * 32 + ak];
#pragma unroll
    for (int j = 0; j < 4; j++) bv[j] = *(const f16x8*)&Bs[(wc * 64 + j * 16 + ar) * 32 + ak];
#pragma unroll
    for (int i = 0; i < 4; i++)
#pragma unroll
      for (int j = 0; j < 4; j++)
        acc[i][j] = __builtin_amdgcn_mfma_f32_16x16x32_f16(av[i], bv[j], acc[i][j], 0, 0, 0);
    __syncthreads();
  }
  const int r0 = (l >> 4) << 2, c0 = l & 15;
#pragma unroll
  for (int i = 0; i < 4; i++) {
#pragma unroll
    for (int j = 0; j < 4; j++) {
      const int col = tn * 128 + wc * 64 + j * 16 + c0;
      const float bc = (EPI & 1) ? bias[col] : 0.f;
#pragma unroll
      for (int r = 0; r < 4; r++) {
        const int row = tm * 128 + wr * 64 + i * 16 + r0 + r;
        float v = acc[i][j][r];
        if (EPI & 1) { v += bc; v = v > 0.f ? v : 0.f; }
        if (EPI & 2) {
          const int b_ = row >> 9, t = row & 511;
          out[((size_t)(t * 64 + b_) << 10) + col] = (f16)v;
        } else {
          out[(size_t)row * N + col] = (f16)v;
        }
      }
    }
  }
}

// ---------------- GEMM with f32 B operand (register-staged f32->f16) ----------------
__global__ __launch_bounds__(256) void gemm_b32(
    const f16* __restrict__ A, int lda, const float* __restrict__ Bw,
    f16* __restrict__ out, int M, int N, int K) {
  __shared__ alignas(16) f16 As[4096];
  __shared__ alignas(16) f16 Bs[4096];
  const int nt = N >> 7;
  const int bx = blockIdx.x;
  const int tm = bx / nt, tn = bx - tm * nt;
  const int tid = threadIdx.x;
  const int l = tid & 63, w = tid >> 6;
  const int wr = w >> 1, wc = w & 1;
  const int srow = (w << 4) + (l >> 2);
  const int scol = (l & 3) << 3;
  const f16* Ab = A + (size_t)(tm * 128 + srow) * lda + scol;
  const int brow = tid >> 1, bcol = (tid & 1) << 4;
  const float* Bb = Bw + (size_t)(tn * 128 + brow) * K + bcol;
  f32x4 acc[4][4];
#pragma unroll
  for (int i = 0; i < 4; i++)
#pragma unroll
    for (int j = 0; j < 4; j++) acc[i][j] = (f32x4){0.f, 0.f, 0.f, 0.f};
  const int ar = l & 15, ak = (l >> 4) << 3;
  for (int k0 = 0; k0 < K; k0 += 32) {
    gld16(Ab + k0, &As[tid * 8]);
    gld16(Ab + (size_t)64 * lda + k0, &As[tid * 8 + 2048]);
    {
      const float* bp = Bb + k0;
      float4 u0 = *(const float4*)(bp + 0), u1 = *(const float4*)(bp + 4);
      float4 u2 = *(const float4*)(bp + 8), u3 = *(const float4*)(bp + 12);
      f16x8 h0 = {(f16)u0.x, (f16)u0.y, (f16)u0.z, (f16)u0.w,
                  (f16)u1.x, (f16)u1.y, (f16)u1.z, (f16)u1.w};
      f16x8 h1 = {(f16)u2.x, (f16)u2.y, (f16)u2.z, (f16)u2.w,
                  (f16)u3.x, (f16)u3.y, (f16)u3.z, (f16)u3.w};
      *(f16x8*)&Bs[brow * 32 + bcol] = h0;
      *(f16x8*)&Bs[brow * 32 + bcol + 8] = h1;
    }
    __syncthreads();
    f16x8 av[4], bv[4];
#pragma unroll
    for (int i = 0; i < 4; i++) av[i] = *(const f16x8*)&As[(wr * 64 + i * 16 + ar) * 32 + ak];
#pragma unroll
    for (int j = 0; j < 4; j++) bv[j] = *(const f16x8*)&Bs[(wc * 64 + j * 16 + ar) * 32 + ak];
#pragma unroll
    for (int i = 0; i < 4; i++)
#pragma unroll
      for (int j = 0; j < 4; j++)
        acc[i][j] = __builtin_amdgcn_mfma_f32_16x16x32_f16(av[i], bv[j], acc[i][j], 0, 0, 0);
    __syncthreads();
  }
  const int r0 = (l >> 4) << 2, c0 = l & 15;
#pragma unroll
  for (int i = 0; i < 4; i++) {
#pragma unroll
    for (int j = 0; j < 4; j++) {
      const int col = tn * 128 + wc * 64 + j * 16 + c0;
#pragma unroll
      for (int r = 0; r < 4; r++) {
        const int row = tm * 128 + wr * 64 + i * 16 + r0 + r;
        out[(size_t)row * N + col] = (f16)acc[i][j][r];
      }
    }
  }
}

// ---------------- GEMM, f32 B, concat-A (A = [A0 | A1], each [M][1024], K=2048) ----------------
__global__ __launch_bounds__(256) void gemm_b32c(
    const f16* __restrict__ A0, const f16* __restrict__ A1, const float* __restrict__ Bw,
    f16* __restrict__ out, int M, int N) {
  constexpr int K = 2048;
  __shared__ alignas(16) f16 As[4096];
  __shared__ alignas(16) f16 Bs[4096];
  const int nt = N >> 7;
  const int bx = blockIdx.x;
  const int tm = bx / nt, tn = bx - tm * nt;
  const int tid = threadIdx.x;
  const int l = tid & 63, w = tid >> 6;
  const int wr = w >> 1, wc = w & 1;
  const int srow = (w << 4) + (l >> 2);
  const int scol = (l & 3) << 3;
  const int brow = tid >> 1, bcol = (tid & 1) << 4;
  const float* Bb = Bw + (size_t)(tn * 128 + brow) * K + bcol;
  f32x4 acc[4][4];
#pragma unroll
  for (int i = 0; i < 4; i++)
#pragma unroll
    for (int j = 0; j < 4; j++) acc[i][j] = (f32x4){0.f, 0.f, 0.f, 0.f};
  const int ar = l & 15, ak = (l >> 4) << 3;
  for (int k0 = 0; k0 < K; k0 += 32) {
    const f16* base = (k0 < 1024) ? A0 : A1;
    const int ko = k0 & 1023;
    const f16* Ab = base + (size_t)(tm * 128 + srow) * 1024 + ko + scol;
    gld16(Ab, &As[tid * 8]);
    gld16(Ab + (size_t)64 * 1024, &As[tid * 8 + 2048]);
    {
      const float* bp = Bb + k0;
      float4 u0 = *(const float4*)(bp + 0), u1 = *(const float4*)(bp + 4);
      float4 u2 = *(const float4*)(bp + 8), u3 = *(const float4*)(bp + 12);
      f16x8 h0 = {(f16)u0.x, (f16)u0.y, (f16)u0.z, (f16)u0.w,
                  (f16)u1.x, (f16)u1.y, (f16)u1.z, (f16)u1.w};
      f16x8 h1 = {(f16)u2.x, (f16)u2.y, (f16)u2.z, (f16)u2.w,
                  (f16)u3.x, (f16)u3.y, (f16)u3.z, (f16)u3.w};
      *(f16x8*)&Bs[brow * 32 + bcol] = h0;
      *(f16x8*)&Bs[brow * 32 + bcol + 8] = h1;
    }
    __syncthreads();
    f16x8 av[4], bv[4];
#pragma unroll
    for (int i = 0; i < 4; i++) av[i] = *(const f16x8*)&As[(wr * 64 + i * 16 + ar) * 32 + ak];
#pragma unroll
    for (int j = 0; j < 4; j++) bv[j] = *(const f16x8*)&Bs[(wc * 64 + j * 16 + ar) * 32 + ak];
#pragma unroll
    for (int i = 0; i < 4; i++)
#pragma unroll
      for (int j = 0; j < 4; j++)
        acc[i][j] = __builtin_amdgcn_mfma_f32_16x16x32_f16(av[i], bv[j], acc[i][j], 0, 0, 0);
    __syncthreads();
  }
  const int r0 = (l >> 4) << 2, c0 = l & 15;
#pragma unroll
  for (int i = 0; i < 4; i++) {
#pragma unroll
    for (int j = 0; j < 4; j++) {
      const int col = tn * 128 + wc * 64 + j * 16 + c0;
#pragma unroll
      for (int r = 0; r < 4; r++) {
        const int row = tm * 128 + wr * 64 + i * 16 + r0 + r;
        out[(size_t)row * N + col] = (f16)acc[i][j][r];
      }
    }
  }
}

// ---------------- fused recurrence (R14 verbatim — fallback only) ----------------
template <int LAYER>
__global__ __launch_bounds__(512, 1) void rnn_scan(
    const f16* __restrict__ X, const float* __restrict__ Wih, const float* __restrict__ Whh,
    const float* __restrict__ bsum, f16* __restrict__ hbuf, unsigned int* __restrict__ flags,
    f16* __restrict__ seqout, float* __restrict__ dout) {
  constexpr int KX = LAYER ? 2048 : 1024;
  constexpr int XSH = LAYER ? 11 : 10;
  constexpr int NKX = KX / 128;
  constexpr int NKH = 8;
  const int bid = blockIdx.x;
  const int g_ = (bid & 7) >> 1;
  const int dir = g_ >> 1, bg = g_ & 1;
  const int cg = ((bid & 1) << 5) | (bid >> 3);
  const int tid = threadIdx.x, l = tid & 63, w = tid >> 6;
  const int mi = w & 1, kq = w >> 1;
  __shared__ alignas(16) f16 Wl[16 * 1024];
  __shared__ alignas(16) f16 Wi[16 * KX];
  __shared__ f32x4 part[2][4][64];
  __shared__ alignas(16) f16 p2[32][16];
  __shared__ unsigned int cnt;
  const int ld = LAYER * 2 + dir;
  if (tid == 0) cnt = 0u;
  for (int ch = tid; ch < 2048; ch += 512) {
    const int n = ch >> 7, k0 = (ch & 127) << 3;
    const float* wp = Whh + (((size_t)(ld * 1024 + cg * 16 + n)) << 10) + k0;
    float4 v0 = *(const float4*)wp, v1 = *(const float4*)(wp + 4);
    f16x8 hv = {(f16)v0.x, (f16)v0.y, (f16)v0.z, (f16)v0.w,
                (f16)v1.x, (f16)v1.y, (f16)v1.z, (f16)v1.w};
    *(f16x8*)&Wl[(n << 10) + (k0 ^ ((n & 7) << 3))] = hv;
  }
  for (int ch = tid; ch < (16 * KX / 8); ch += 512) {
    const int n = ch >> (XSH - 3), k0 = (ch & (KX / 8 - 1)) << 3;
    const float* wp = Wih + ((size_t)(dir * 1024 + cg * 16 + n)) * KX + k0;
    float4 v0 = *(const float4*)wp, v1 = *(const float4*)(wp + 4);
    f16x8 hv = {(f16)v0.x, (f16)v0.y, (f16)v0.z, (f16)v0.w,
                (f16)v1.x, (f16)v1.y, (f16)v1.z, (f16)v1.w};
    *(f16x8*)&Wi[(n << XSH) + (k0 ^ ((n & 7) << 3))] = hv;
  }
  const float bn = bsum[(ld << 10) + cg * 16 + (l & 15)];
  f16* hD = hbuf + ((size_t)dir << 17);
  unsigned int* fl = flags + ((dir * 2 + bg) << 10);
  const int arow = bg * 32 + mi * 16 + (l & 15);
  const int akh = (kq << 8) + ((l >> 4) << 3);
  const int akx = kq * (KX / 4) + ((l >> 4) << 3);
  const int wn = l & 15;
  const int wsw = (wn & 7) << 3;

  f16x8 xv[NKX];
  {
    const int t0 = dir ? 511 : 0;
    const f16* xr = X + (((size_t)(t0 * 64 + arow)) << XSH) + akx;
#pragma unroll
    for (int i = 0; i < NKX; i++)
      asm volatile("global_load_dwordx4 %0, %1, off offset:%2"
                   : "=&v"(xv[i]) : "v"(xr), "i"(64 * i));
  }
  __syncthreads();

  for (int s = 0; s < 512; ++s) {
    const int t = dir ? (511 - s) : s;
    f32x4 acc = {0.f, 0.f, 0.f, 0.f};
    if (s > 0) {
      if (w == 7) {
        const unsigned int tgt = (unsigned int)(LAYER * 512 + s);
        unsigned int* fp = fl + l * 16;
        for (;;) {
          unsigned int f = __hip_atomic_load(fp, __ATOMIC_RELAXED, __HIP_MEMORY_SCOPE_AGENT);
          if (__all((int)(f >= tgt))) break;
        }
      }
      __syncthreads();
      const f16* hrow = hD + (((size_t)(s & 1)) << 16) + (((size_t)arow) << 10) + akh;
      f16x8 hv[NKH];
#pragma unroll
      for (int i = 0; i < NKH; i++)
        asm volatile("global_load_dwordx4 %0, %1, off offset:%2 sc0 sc1"
                     : "=&v"(hv[i]) : "v"(hrow), "i"(64 * i));
      asm volatile("s_waitcnt vmcnt(%0)" :: "i"(NKH) : "memory");
      __builtin_amdgcn_sched_barrier(0);
#pragma unroll
      for (int it = 0; it < NKX; ++it) {
        const int ko = akx + it * 32;
        f16x8 bv = *(const f16x8*)&Wi[(wn << XSH) + (ko ^ wsw)];
        acc = __builtin_amdgcn_mfma_f32_16x16x32_f16(xv[it], bv, acc, 0, 0, 0);
      }
      asm volatile("s_waitcnt vmcnt(0)" ::: "memory");
      __builtin_amdgcn_sched_barrier(0);
#pragma unroll
      for (int it = 0; it < NKH; ++it) {
        const int ko = akh + it * 32;
        f16x8 bv = *(const f16x8*)&Wl[(wn << 10) + (ko ^ wsw)];
        acc = __builtin_amdgcn_mfma_f32_16x16x32_f16(hv[it], bv, acc, 0, 0, 0);
      }
    } else {
      asm volatile("s_waitcnt vmcnt(0)" ::: "memory");
      __builtin_amdgcn_sched_barrier(0);
#pragma unroll
      for (int it = 0; it < NKX; ++it) {
        const int ko = akx + it * 32;
        f16x8 bv = *(const f16x8*)&Wi[(wn << XSH) + (ko ^ wsw)];
        acc = __builtin_amdgcn_mfma_f32_16x16x32_f16(xv[it], bv, acc, 0, 0, 0);
      }
    }
    part[mi][kq][l] = acc;
    __syncthreads();
    if (w < 2) {
      f32x4 sum = part[w][0][l];
      sum += part[w][1][l];
      sum += part[w][2][l];
      sum += part[w][3][l];
#pragma unroll
      for (int r = 0; r < 4; ++r) {
        const int row = ((l >> 4) << 2) + r;
        float v = tanh_fast(sum[r] + bn);
        p2[(w << 4) + row][l & 15] = (f16)v;
        if (s == 511) {
          const int b_ = bg * 32 + (w << 4) + row;
          dout[(((size_t)(ld * 64 + b_)) << 10) + cg * 16 + (l & 15)] = v;
        }
      }
      asm volatile("s_waitcnt lgkmcnt(0)" ::: "memory");
      __builtin_amdgcn_sched_barrier(0);
      if (l < 32) {
        const int rr = (w << 4) + (l >> 1), hf = l & 1;
        f16x8 pv = *(const f16x8*)&p2[rr][hf * 8];
        const int b_ = bg * 32 + rr;
        f16* hp = hD + (((size_t)((s + 1) & 1)) << 16) + (((size_t)b_) << 10) + cg * 16 + hf * 8;
        asm volatile("global_store_dwordx4 %0, %1, off sc0 sc1" :: "v"(hp), "v"(pv) : "memory");
        if (LAYER == 0) {
          f16* sp = seqout + (((size_t)(t * 64 + b_)) << 11) + (dir << 10) + cg * 16 + hf * 8;
          asm volatile("global_store_dwordx4 %0, %1, off" :: "v"(sp), "v"(pv) : "memory");
        }
      }
      asm volatile("s_waitcnt vmcnt(0)" ::: "memory");
      __builtin_amdgcn_sched_barrier(0);
      if (l == 0) {
        unsigned int old = __hip_atomic_fetch_add(&cnt, 1u, __ATOMIC_RELAXED,
                                                  __HIP_MEMORY_SCOPE_WORKGROUP);
        if (old == (unsigned int)(2 * s + 1))
          __hip_atomic_store(&fl[cg * 16], (unsigned int)(LAYER * 512 + s + 1),
                             __ATOMIC_RELAXED, __HIP_MEMORY_SCOPE_AGENT);
      }
    }
    if (s + 1 < 512) {
      const int tn_ = dir ? (511 - (s + 1)) : (s + 1);
      const f16* xr = X + (((size_t)(tn_ * 64 + arow)) << XSH) + akx;
#pragma unroll
      for (int i = 0; i < NKX; i++)
        asm volatile("global_load_dwordx4 %0, %1, off offset:%2"
                     : "=&v"(xv[i]) : "v"(xr), "i"(64 * i));
    }
  }
}

// ---------------- PRE recurrence (padded flags, all-asm VMEM — R17-proven) ----------------
// LAYER==0: reducers overlay layer-0 output IN PLACE onto the consumed PRE tile.
template <int LAYER>
__global__ __launch_bounds__(512, 1) void rnn_scan_pre(
    f16* __restrict__ PRE0, f16* __restrict__ PRE1,
    const float* __restrict__ Whh, const float* __restrict__ bsum,
    f16* __restrict__ hbuf, unsigned int* __restrict__ flags,  // [4][64][16] u32 padded, zeroed
    float* __restrict__ dout) {
  constexpr int NKH = 8;
  const int bid = blockIdx.x;
  const int g_ = (bid & 7) >> 1;
  const int dir = g_ >> 1, bg = g_ & 1;
  const int cg = ((bid & 1) << 5) | (bid >> 3);
  const int tid = threadIdx.x, l = tid & 63, w = tid >> 6;
  const int mi = w & 1, kq = w >> 1;
  __shared__ alignas(16) f16 Wl[16 * 1024];
  __shared__ f32x4 part[2][4][64];
  __shared__ alignas(16) f16 p2[32][16];
  __shared__ unsigned int cnt;
  const int ld = LAYER * 2 + dir;
  if (tid == 0) cnt = 0u;
  for (int ch = tid; ch < 2048; ch += 512) {
    const int n = ch >> 7, k0 = (ch & 127) << 3;
    const float* wp = Whh + (((size_t)(ld * 1024 + cg * 16 + n)) << 10) + k0;
    float4 v0 = *(const float4*)wp, v1 = *(const float4*)(wp + 4);
    f16x8 hv = {(f16)v0.x, (f16)v0.y, (f16)v0.z, (f16)v0.w,
                (f16)v1.x, (f16)v1.y, (f16)v1.z, (f16)v1.w};
    *(f16x8*)&Wl[(n << 10) + (k0 ^ ((n & 7) << 3))] = hv;
  }
  const int pcol = cg * 16 + (l & 15);
  const float bn = bsum[(ld << 10) + pcol];
  f16* preD = dir ? PRE1 : PRE0;
  f16* hD = hbuf + ((size_t)dir << 17);
  unsigned int* fl = flags + ((dir * 2 + bg) << 10);
  const int arow = bg * 32 + mi * 16 + (l & 15);
  const int akh = (kq << 8) + ((l >> 4) << 3);
  const int wn = l & 15;
  const int wsw = (wn & 7) << 3;
  const int prow = bg * 32 + (w << 4) + ((l >> 4) << 2);

  unsigned int pu0 = 0, pu1 = 0, pu2 = 0, pu3 = 0;
  if (w < 2) {
    const int t0 = dir ? 511 : 0;
    const f16* ppA = preD + (((size_t)(t0 * 64 + prow)) << 10) + pcol;
    const f16* ppB = ppA + 2048;
    asm volatile("global_load_ushort %0, %1, off" : "=&v"(pu0) : "v"(ppA));
    asm volatile("global_load_ushort %0, %1, off offset:2048" : "=&v"(pu1) : "v"(ppA));
    asm volatile("global_load_ushort %0, %1, off" : "=&v"(pu2) : "v"(ppB));
    asm volatile("global_load_ushort %0, %1, off offset:2048" : "=&v"(pu3) : "v"(ppB));
  }
  __syncthreads();

  for (int s = 0; s < 512; ++s) {
    const int t = dir ? (511 - s) : s;
    f32x4 acc = {0.f, 0.f, 0.f, 0.f};
    if (s > 0) {
      if (w == 7) {
        const unsigned int tgt = (unsigned int)s;
        unsigned int* fp = fl + l * 16;
        for (;;) {
          unsigned int f = __hip_atomic_load(fp, __ATOMIC_RELAXED, __HIP_MEMORY_SCOPE_AGENT);
          if (__all((int)(f >= tgt))) break;
        }
      }
      __syncthreads();
      const f16* hrow = hD + (((size_t)(s & 1)) << 16) + (((size_t)arow) << 10) + akh;
      f16x8 hv[NKH];
#pragma unroll
      for (int i = 0; i < NKH; i++)
        asm volatile("global_load_dwordx4 %0, %1, off offset:%2 sc0 sc1"
                     : "=&v"(hv[i]) : "v"(hrow), "i"(64 * i));
      asm volatile("s_waitcnt vmcnt(0)" ::: "memory");
      __builtin_amdgcn_sched_barrier(0);
#pragma unroll
      for (int it = 0; it < NKH; ++it) {
        const int ko = akh + it * 32;
        f16x8 bv = *(const f16x8*)&Wl[(wn << 10) + (ko ^ wsw)];
        acc = __builtin_amdgcn_mfma_f32_16x16x32_f16(hv[it], bv, acc, 0, 0, 0);
      }
    }
    part[mi][kq][l] = acc;
    __syncthreads();
    if (w < 2) {
      asm volatile("s_waitcnt vmcnt(0)" ::: "memory");  // pre regs ready (s=0 prologue case)
      __builtin_amdgcn_sched_barrier(0);
      float pva[4];
      pva[0] = (float)__builtin_bit_cast(f16, (unsigned short)pu0);
      pva[1] = (float)__builtin_bit_cast(f16, (unsigned short)pu1);
      pva[2] = (float)__builtin_bit_cast(f16, (unsigned short)pu2);
      pva[3] = (float)__builtin_bit_cast(f16, (unsigned short)pu3);
      f32x4 sum = part[w][0][l];
      sum += part[w][1][l];
      sum += part[w][2][l];
      sum += part[w][3][l];
#pragma unroll
      for (int r = 0; r < 4; ++r) {
        const int row = ((l >> 4) << 2) + r;
        float v = tanh_fast(sum[r] + pva[r] + bn);
        p2[(w << 4) + row][l & 15] = (f16)v;
        if (s == 511) {
          const int b_ = bg * 32 + (w << 4) + row;
          dout[(((size_t)(ld * 64 + b_)) << 10) + pcol] = v;
        }
      }
      asm volatile("s_waitcnt lgkmcnt(0)" ::: "memory");
      __builtin_amdgcn_sched_barrier(0);
      if (l < 32) {
        const int rr = (w << 4) + (l >> 1), hf = l & 1;
        f16x8 pv = *(const f16x8*)&p2[rr][hf * 8];
        const int b_ = bg * 32 + rr;
        f16* hp = hD + (((size_t)((s + 1) & 1)) << 16) + (((size_t)b_) << 10) + cg * 16 + hf * 8;
        asm volatile("global_store_dwordx4 %0, %1, off sc0 sc1" :: "v"(hp), "v"(pv) : "memory");
        if (LAYER == 0) {
          f16* xp = preD + (((size_t)(t * 64 + b_)) << 10) + cg * 16 + hf * 8;
          asm volatile("global_store_dwordx4 %0, %1, off" :: "v"(xp), "v"(pv) : "memory");
        }
      }
      asm volatile("s_waitcnt vmcnt(0)" ::: "memory");
      __builtin_amdgcn_sched_barrier(0);
      if (l == 0) {
        unsigned int old = __hip_atomic_fetch_add(&cnt, 1u, __ATOMIC_RELAXED,
                                                  __HIP_MEMORY_SCOPE_WORKGROUP);
        if (old == (unsigned int)(2 * s + 1))
          __hip_atomic_store(&fl[cg * 16], (unsigned int)(s + 1),
                             __ATOMIC_RELAXED, __HIP_MEMORY_SCOPE_AGENT);
      }
      if (s + 1 < 512) {  // single asm issue site, after publish
        const int tn_ = dir ? (511 - (s + 1)) : (s + 1);
        const f16* ppA = preD + (((size_t)(tn_ * 64 + prow)) << 10) + pcol;
        const f16* ppB = ppA + 2048;
        asm volatile("global_load_ushort %0, %1, off" : "=&v"(pu0) : "v"(ppA));
        asm volatile("global_load_ushort %0, %1, off offset:2048" : "=&v"(pu1) : "v"(ppA));
        asm volatile("global_load_ushort %0, %1, off" : "=&v"(pu2) : "v"(ppB));
        asm volatile("global_load_ushort %0, %1, off offset:2048" : "=&v"(pu3) : "v"(ppB));
      }
    }
  }
}

// ---------------- launch ----------------

extern "C" void kernel_launch(void* const* d_in, const int* in_sizes, int n_in,
                              void* d_out, int out_size, void* d_ws, size_t ws_size,
                              hipStream_t stream) {
  const int* src    = (const int*)d_in[0];
  const float* emb  = (const float*)d_in[1];
  const float* W1   = (const float*)d_in[2];
  const float* b1   = (const float*)d_in[3];
  const float* W2   = (const float*)d_in[4];
  const float* b2   = (const float*)d_in[5];
  const float* Wih0 = (const float*)d_in[6];
  const float* WihL = (const float*)d_in[7];
  const float* Whh  = (const float*)d_in[8];
  const float* bih  = (const float*)d_in[9];
  const float* bhh  = (const float*)d_in[10];
  float* out = (float*)d_out;
  char* ws = (char*)d_ws;

  if (ws_size < WS_NEED) {  // diagnostic fallback
    zero_k<<<(out_size + 255) / 256, 256, 0, stream>>>((unsigned int*)d_out, out_size);
    return;
  }

  if (ws_size >= WS_NEED2) {
    // ================= all-PRE path (256MB) =================
    f16* X0    = (f16*)(ws + Q_X0);
    f16* EMB   = (f16*)(ws + Q_EMB);
    f16* MLP1  = (f16*)(ws + Q_MLP1);
    f16* W1C   = (f16*)(ws + Q_W1C);
    f16* W2C   = (f16*)(ws + Q_W2C);
    f16* PRE0D0 = (f16*)(ws + Q_PRE0D0);
    f16* PRE0D1 = (f16*)(ws + Q_PRE0D1);
    f16* HB0   = (f16*)(ws + Q_HB0);
    unsigned int* FL0 = (unsigned int*)(ws + Q_FL0);
    float* BIAS0 = (float*)(ws + Q_BIAS0);
    f16* PRE1D0 = (f16*)(ws + Q_PRE1D0);
    f16* PRE1D1 = (f16*)(ws + Q_PRE1D1);
    f16* HB1   = (f16*)(ws + Q_HB1);
    unsigned int* FL1 = (unsigned int*)(ws + Q_FL1);
    float* BIAS1 = (float*)(ws + Q_BIAS1);

    cvt_k<<<256, 256, 0, stream>>>(W1, W1C, 131072);
    cvt_k<<<256, 256, 0, stream>>>(W2, W2C, 262144);

    embed_k<<<32768, 128, 0, stream>>>(src, emb, EMB);
    gemm_f16<1><<<2048, 256, 0, stream>>>(EMB, 512, W1C, MLP1, b1, 32768, 1024, 512);
    gemm_f16<3><<<2048, 256, 0, stream>>>(MLP1, 1024, W2C, X0, b2, 32768, 1024, 1024);

    gemm_b32<<<2048, 256, 0, stream>>>(X0, 1024, Wih0, PRE0D0, 32768, 1024, 1024);
    gemm_b32<<<2048, 256, 0, stream>>>(X0, 1024, Wih0 + (1u << 20), PRE0D1, 32768, 1024, 1024);
    zero_k<<<16, 256, 0, stream>>>(FL0, 4096);
    bias_k<<<16, 256, 0, stream>>>(bih, bhh, BIAS0);
    rnn_scan_pre<0><<<256, 512, 0, stream>>>(PRE0D0, PRE0D1, Whh, BIAS0, HB0, FL0, out);

    gemm_b32c<<<2048, 256, 0, stream>>>(PRE0D0, PRE0D1, WihL, PRE1D0, 32768, 1024);
    gemm_b32c<<<2048, 256, 0, stream>>>(PRE0D0, PRE0D1, WihL + (1u << 21), PRE1D1, 32768, 1024);
    zero_k<<<16, 256, 0, stream>>>(FL1, 4096);
    bias_k<<<16, 256, 0, stream>>>(bih, bhh, BIAS1);
    rnn_scan_pre<1><<<256, 512, 0, stream>>>(PRE1D0, PRE1D1, Whh, BIAS1, HB1, FL1, out);
    return;
  }

  // ================= fused fallback (R14, 196MB) =================
  f16* X0   = (f16*)(ws + OFF_X0);
  f16* X1   = (f16*)(ws + OFF_X1);
  f16* EMB  = (f16*)(ws + OFF_EMB);
  f16* MLP1 = (f16*)(ws + OFF_MLP1);
  f16* HB   = (f16*)(ws + OFF_H);
  unsigned int* FLAGS = (unsigned int*)(ws + OFF_FLAGS);
  float* BIAS = (float*)(ws + OFF_BIAS);
  f16* W1C  = (f16*)(ws + OFF_W1C);
  f16* W2C  = (f16*)(ws + OFF_W2C);

  cvt_k<<<256, 256, 0, stream>>>(W1, W1C, 131072);
  cvt_k<<<256, 256, 0, stream>>>(W2, W2C, 262144);
  bias_k<<<16, 256, 0, stream>>>(bih, bhh, BIAS);
  zero_k<<<16, 256, 0, stream>>>(FLAGS, 4096);

  embed_k<<<32768, 128, 0, stream>>>(src, emb, EMB);
  gemm_f16<1><<<2048, 256, 0, stream>>>(EMB, 512, W1C, MLP1, b1, 32768, 1024, 512);
  gemm_f16<3><<<2048, 256, 0, stream>>>(MLP1, 1024, W2C, X0, b2, 32768, 1024, 1024);

  rnn_scan<0><<<256, 512, 0, stream>>>(X0, Wih0, Whh, BIAS, HB, FLAGS, X1, out);
  rnn_scan<1><<<256, 512, 0, stream>>>(X1, WihL, Whh, BIAS, HB, FLAGS, nullptr, out);
}

// Round 20
// 4761.703 us; speedup vs baseline: 1.4701x; 1.0499x over previous
//
#include <hip/hip_runtime.h>

// RNNEncModel: embed -> MLP(relu x2) -> 2x bidirectional tanh-RNN -> final states [4,64,1024] f32.
// B=64 T=512 E=512 H=1024 V=32000.
// Round-20: R19 all-PRE structure, scan restructured to FULL-K waves: each compute wave owns its
// 16-row x 16-col tile across all K=1024 (32 laddered MFMAs) -> deletes the cross-wave K-reduce
// (part LDS) and the second barrier; block shrinks to 4 waves (w0/w1 compute+publish, w3 polls).
// Everything proven kept: padded flags + single poller, all-asm VMEM (R16), single issue sites
// (R7), XCD swizzle, in-place X1 overlay. ws>=256MB: all-PRE; else R14 fused fallback.

typedef _Float16 f16;
typedef _Float16 f16x8 __attribute__((ext_vector_type(8)));
typedef _Float16 f16x4 __attribute__((ext_vector_type(4)));
typedef float f32x4 __attribute__((ext_vector_type(4)));

static const size_t MB_ = 1024ull * 1024ull;
// ---- fused fallback layout (R14, 196MB) ----
static const size_t OFF_X0    = 0;
static const size_t OFF_X1    = 64 * MB_;
static const size_t OFF_EMB   = OFF_X1;
static const size_t OFF_MLP1  = 96 * MB_;
static const size_t OFF_H     = 192 * MB_;
static const size_t OFF_FLAGS = 192 * MB_ + 512 * 1024;
static const size_t OFF_BIAS  = 192 * MB_ + 576 * 1024;
static const size_t OFF_W1C   = 193 * MB_;
static const size_t OFF_W2C   = 194 * MB_;
static const size_t WS_NEED   = 196 * MB_;
// ---- all-PRE layout (256MB) ----
static const size_t Q_X0     = 0;
static const size_t Q_EMB    = 64 * MB_;
static const size_t Q_MLP1   = 96 * MB_;
static const size_t Q_W1C    = 160 * MB_;
static const size_t Q_W2C    = 161 * MB_;
static const size_t Q_PRE0D0 = 64 * MB_;
static const size_t Q_PRE0D1 = 128 * MB_;
static const size_t Q_HB0    = 192 * MB_;
static const size_t Q_FL0    = 192 * MB_ + 512 * 1024;
static const size_t Q_BIAS0  = 192 * MB_ + 544 * 1024;
static const size_t Q_PRE1D0 = 0;
static const size_t Q_PRE1D1 = 192 * MB_;
static const size_t Q_HB1    = 64 * MB_;
static const size_t Q_FL1    = 64 * MB_ + 512 * 1024;
static const size_t Q_BIAS1  = 64 * MB_ + 544 * 1024;
static const size_t WS_NEED2 = 256 * MB_;

__device__ __forceinline__ void gld16(const void* g, void* l) {
#if __has_builtin(__builtin_amdgcn_global_load_lds)
  __builtin_amdgcn_global_load_lds((const __attribute__((address_space(1))) void*)g,
                                   (__attribute__((address_space(3))) void*)l, 16, 0, 0);
#else
  *(f16x8*)l = *(const f16x8*)g;
#endif
}

// fast tanh: tanh(|x|) = 1 - 2/(exp2(2*log2e*|x|)+1); hw exp + rcp, abs err ~1e-6 << f16 rounding.
__device__ __forceinline__ float tanh_fast(float x) {
  float ax = __builtin_fabsf(x);
  float e = __builtin_amdgcn_exp2f(ax * 2.8853900817779268f);
  float r = 1.0f - 2.0f * __builtin_amdgcn_rcpf(e + 1.0f);
  return __builtin_copysignf(r, x);
}

// ---------------- utility kernels ----------------

__global__ void zero_k(unsigned int* __restrict__ p, int n) {
  int i = blockIdx.x * blockDim.x + threadIdx.x;
  if (i < n) p[i] = 0u;
}

__global__ void cvt_k(const float* __restrict__ in, f16* __restrict__ out, int n4) {
  int i = blockIdx.x * blockDim.x + threadIdx.x;
  int stride = gridDim.x * blockDim.x;
  for (; i < n4; i += stride) {
    float4 v = ((const float4*)in)[i];
    f16x4 o = {(f16)v.x, (f16)v.y, (f16)v.z, (f16)v.w};
    ((f16x4*)out)[i] = o;
  }
}

__global__ void bias_k(const float* __restrict__ a, const float* __restrict__ b, float* __restrict__ o) {
  int i = blockIdx.x * blockDim.x + threadIdx.x;
  if (i < 4096) o[i] = a[i] + b[i];
}

// embedding gather + f16 convert; padding_idx=0 -> zero row
__global__ void embed_k(const int* __restrict__ src, const float* __restrict__ tab, f16* __restrict__ out) {
  int m = blockIdx.x;
  int tid = threadIdx.x;
  int tok = src[m];
  f16x4 o = {(f16)0.f, (f16)0.f, (f16)0.f, (f16)0.f};
  if (tok != 0) {
    float4 v = *(const float4*)(tab + (size_t)tok * 512 + tid * 4);
    o[0] = (f16)v.x; o[1] = (f16)v.y; o[2] = (f16)v.z; o[3] = (f16)v.w;
  }
  *(f16x4*)(out + (size_t)m * 512 + tid * 4) = o;
}

// ---------------- GEMM: C[M,N] = A[M,K(lda)] * Bw[N,K]^T (B f16) ----------------
template <int EPI>
__global__ __launch_bounds__(256) void gemm_f16(
    const f16* __restrict__ A, int lda, const f16* __restrict__ Bw,
    f16* __restrict__ out, const float* __restrict__ bias, int M, int N, int K) {
  __shared__ alignas(16) f16 As[4096];
  __shared__ alignas(16) f16 Bs[4096];
  const int nt = N >> 7;
  const int bx = blockIdx.x;
  const int tm = bx / nt, tn = bx - tm * nt;
  const int tid = threadIdx.x;
  const int l = tid & 63, w = tid >> 6;
  const int wr = w >> 1, wc = w & 1;
  const int srow = (w << 4) + (l >> 2);
  const int scol = (l & 3) << 3;
  const f16* Ab = A + (size_t)(tm * 128 + srow) * lda + scol;
  const f16* Bb = Bw + (size_t)(tn * 128 + srow) * K + scol;
  f32x4 acc[4][4];
#pragma unroll
  for (int i = 0; i < 4; i++)
#pragma unroll
    for (int j = 0; j < 4; j++) acc[i][j] = (f32x4){0.f, 0.f, 0.f, 0.f};
  const int ar = l & 15, ak = (l >> 4) << 3;
  for (int k0 = 0; k0 < K; k0 += 32) {
    gld16(Ab + k0, &As[tid * 8]);
    gld16(Ab + (size_t)64 * lda + k0, &As[tid * 8 + 2048]);
    gld16(Bb + k0, &Bs[tid * 8]);
    gld16(Bb + (size_t)64 * K + k0, &Bs[tid * 8 + 2048]);
    __syncthreads();
    f16x8 av[4], bv[4];
#pragma unroll
    for (int i = 0; i < 4; i++) av[i] = *(const f16x8*)&As[(wr * 64 + i * 16 + ar) * 32 + ak];
#pragma unroll
    for (int j = 0; j < 4; j++) bv[j] = *(const f16x8*)&Bs[(wc * 64 + j * 16 + ar) * 32 + ak];
#pragma unroll
    for (int i = 0; i < 4; i++)
#pragma unroll
      for (int j = 0; j < 4; j++)
        acc[i][j] = __builtin_amdgcn_mfma_f32_16x16x32_f16(av[i], bv[j], acc[i][j], 0, 0, 0);
    __syncthreads();
  }
  const int r0 = (l >> 4) << 2, c0 = l & 15;
#pragma unroll
  for (int i = 0; i < 4; i++) {
#pragma unroll
    for (int j = 0; j < 4; j++) {
      const int col = tn * 128 + wc * 64 + j * 16 + c0;
      const float bc = (EPI & 1) ? bias[col] : 0.f;
#pragma unroll
      for (int r = 0; r < 4; r++) {
        const int row = tm * 128 + wr * 64 + i * 16 + r0 + r;
        float v = acc[i][j][r];
        if (EPI & 1) { v += bc; v = v > 0.f ? v : 0.f; }
        if (EPI & 2) {
          const int b_ = row >> 9, t = row & 511;
          out[((size_t)(t * 64 + b_) << 10) + col] = (f16)v;
        } else {
          out[(size_t)row * N + col] = (f16)v;
        }
      }
    }
  }
}

// ---------------- GEMM with f32 B operand (register-staged f32->f16) ----------------
__global__ __launch_bounds__(256) void gemm_b32(
    const f16* __restrict__ A, int lda, const float* __restrict__ Bw,
    f16* __restrict__ out, int M, int N, int K) {
  __shared__ alignas(16) f16 As[4096];
  __shared__ alignas(16) f16 Bs[4096];
  const int nt = N >> 7;
  const int bx = blockIdx.x;
  const int tm = bx / nt, tn = bx - tm * nt;
  const int tid = threadIdx.x;
  const int l = tid & 63, w = tid >> 6;
  const int wr = w >> 1, wc = w & 1;
  const int srow = (w << 4) + (l >> 2);
  const int scol = (l & 3) << 3;
  const f16* Ab = A + (size_t)(tm * 128 + srow) * lda + scol;
  const int brow = tid >> 1, bcol = (tid & 1) << 4;
  const float* Bb = Bw + (size_t)(tn * 128 + brow) * K + bcol;
  f32x4 acc[4][4];
#pragma unroll
  for (int i = 0; i < 4; i++)
#pragma unroll
    for (int j = 0; j < 4; j++) acc[i][j] = (f32x4){0.f, 0.f, 0.f, 0.f};
  const int ar = l & 15, ak = (l >> 4) << 3;
  for (int k0 = 0; k0 < K; k0 += 32) {
    gld16(Ab + k0, &As[tid * 8]);
    gld16(Ab + (size_t)64 * lda + k0, &As[tid * 8 + 2048]);
    {
      const float* bp = Bb + k0;
      float4 u0 = *(const float4*)(bp + 0), u1 = *(const float4*)(bp + 4);
      float4 u2 = *(const float4*)(bp + 8), u3 = *(const float4*)(bp + 12);
      f16x8 h0 = {(f16)u0.x, (f16)u0.y, (f16)u0.z, (f16)u0.w,
                  (f16)u1.x, (f16)u1.y, (f16)u1.z, (f16)u1.w};
      f16x8 h1 = {(f16)u2.x, (f16)u2.y, (f16)u2.z, (f16)u2.w,
                  (f16)u3.x, (f16)u3.y, (f16)u3.z, (f16)u3.w};
      *(f16x8*)&Bs[brow * 32 + bcol] = h0;
      *(f16x8*)&Bs[brow * 32 + bcol + 8] = h1;
    }
    __syncthreads();
    f16x8 av[4], bv[4];
#pragma unroll
    for (int i = 0; i < 4; i++) av[i] = *(const f16x8*)&As[(wr * 64 + i * 16 + ar) * 32 + ak];
#pragma unroll
    for (int j = 0; j < 4; j++) bv[j] = *(const f16x8*)&Bs[(wc * 64 + j * 16 + ar) * 32 + ak];
#pragma unroll
    for (int i = 0; i < 4; i++)
#pragma unroll
      for (int j = 0; j < 4; j++)
        acc[i][j] = __builtin_amdgcn_mfma_f32_16x16x32_f16(av[i], bv[j], acc[i][j], 0, 0, 0);
    __syncthreads();
  }
  const int r0 = (l >> 4) << 2, c0 = l & 15;
#pragma unroll
  for (int i = 0; i < 4; i++) {
#pragma unroll
    for (int j = 0; j < 4; j++) {
      const int col = tn * 128 + wc * 64 + j * 16 + c0;
#pragma unroll
      for (int r = 0; r < 4; r++) {
        const int row = tm * 128 + wr * 64 + i * 16 + r0 + r;
        out[(size_t)row * N + col] = (f16)acc[i][j][r];
      }
    }
  }
}

// ---------------- GEMM, f32 B, concat-A (A = [A0 | A1], each [M][1024], K=2048) ----------------
__global__ __launch_bounds__(256) void gemm_b32c(
    const f16* __restrict__ A0, const f16* __restrict__ A1, const float* __restrict__ Bw,
    f16* __restrict__ out, int M, int N) {
  constexpr int K = 2048;
  __shared__ alignas(16) f16 As[4096];
  __shared__ alignas(16) f16 Bs[4096];
  const int nt = N >> 7;
  const int bx = blockIdx.x;
  const int tm = bx / nt, tn = bx - tm * nt;
  const int tid = threadIdx.x;
  const int l = tid & 63, w = tid >> 6;
  const int wr = w >> 1, wc = w & 1;
  const int srow = (w << 4) + (l >> 2);
  const int scol = (l & 3) << 3;
  const int brow = tid >> 1, bcol = (tid & 1) << 4;
  const float* Bb = Bw + (size_t)(tn * 128 + brow) * K + bcol;
  f32x4 acc[4][4];
#pragma unroll
  for (int i = 0; i < 4; i++)
#pragma unroll
    for (int j = 0; j < 4; j++) acc[i][j] = (f32x4){0.f, 0.f, 0.f, 0.f};
  const int ar = l & 15, ak = (l >> 4) << 3;
  for (int k0 = 0; k0 < K; k0 += 32) {
    const f16* base = (k0 < 1024) ? A0 : A1;
    const int ko = k0 & 1023;
    const f16* Ab = base + (size_t)(tm * 128 + srow) * 1024 + ko + scol;
    gld16(Ab, &As[tid * 8]);
    gld16(Ab + (size_t)64 * 1024, &As[tid * 8 + 2048]);
    {
      const float* bp = Bb + k0;
      float4 u0 = *(const float4*)(bp + 0), u1 = *(const float4*)(bp + 4);
      float4 u2 = *(const float4*)(bp + 8), u3 = *(const float4*)(bp + 12);
      f16x8 h0 = {(f16)u0.x, (f16)u0.y, (f16)u0.z, (f16)u0.w,
                  (f16)u1.x, (f16)u1.y, (f16)u1.z, (f16)u1.w};
      f16x8 h1 = {(f16)u2.x, (f16)u2.y, (f16)u2.z, (f16)u2.w,
                  (f16)u3.x, (f16)u3.y, (f16)u3.z, (f16)u3.w};
      *(f16x8*)&Bs[brow * 32 + bcol] = h0;
      *(f16x8*)&Bs[brow * 32 + bcol + 8] = h1;
    }
    __syncthreads();
    f16x8 av[4], bv[4];
#pragma unroll
    for (int i = 0; i < 4; i++) av[i] = *(const f16x8*)&As[(wr * 64 + i * 16 + ar) * 32 + ak];
#pragma unroll
    for (int j = 0; j < 4; j++) bv[j] = *(const f16x8*)&Bs[(wc * 64 + j * 16 + ar) * 32 + ak];
#pragma unroll
    for (int i = 0; i < 4; i++)
#pragma unroll
      for (int j = 0; j < 4; j++)
        acc[i][j] = __builtin_amdgcn_mfma_f32_16x16x32_f16(av[i], bv[j], acc[i][j], 0, 0, 0);
    __syncthreads();
  }
  const int r0 = (l >> 4) << 2, c0 = l & 15;
#pragma unroll
  for (int i = 0; i < 4; i++) {
#pragma unroll
    for (int j = 0; j < 4; j++) {
      const int col = tn * 128 + wc * 64 + j * 16 + c0;
#pragma unroll
      for (int r = 0; r < 4; r++) {
        const int row = tm * 128 + wr * 64 + i * 16 + r0 + r;
        out[(size_t)row * N + col] = (f16)acc[i][j][r];
      }
    }
  }
}

// ---------------- fused recurrence (R14 verbatim — fallback only) ----------------
template <int LAYER>
__global__ __launch_bounds__(512, 1) void rnn_scan(
    const f16* __restrict__ X, const float* __restrict__ Wih, const float* __restrict__ Whh,
    const float* __restrict__ bsum, f16* __restrict__ hbuf, unsigned int* __restrict__ flags,
    f16* __restrict__ seqout, float* __restrict__ dout) {
  constexpr int KX = LAYER ? 2048 : 1024;
  constexpr int XSH = LAYER ? 11 : 10;
  constexpr int NKX = KX / 128;
  constexpr int NKH = 8;
  const int bid = blockIdx.x;
  const int g_ = (bid & 7) >> 1;
  const int dir = g_ >> 1, bg = g_ & 1;
  const int cg = ((bid & 1) << 5) | (bid >> 3);
  const int tid = threadIdx.x, l = tid & 63, w = tid >> 6;
  const int mi = w & 1, kq = w >> 1;
  __shared__ alignas(16) f16 Wl[16 * 1024];
  __shared__ alignas(16) f16 Wi[16 * KX];
  __shared__ f32x4 part[2][4][64];
  __shared__ alignas(16) f16 p2[32][16];
  __shared__ unsigned int cnt;
  const int ld = LAYER * 2 + dir;
  if (tid == 0) cnt = 0u;
  for (int ch = tid; ch < 2048; ch += 512) {
    const int n = ch >> 7, k0 = (ch & 127) << 3;
    const float* wp = Whh + (((size_t)(ld * 1024 + cg * 16 + n)) << 10) + k0;
    float4 v0 = *(const float4*)wp, v1 = *(const float4*)(wp + 4);
    f16x8 hv = {(f16)v0.x, (f16)v0.y, (f16)v0.z, (f16)v0.w,
                (f16)v1.x, (f16)v1.y, (f16)v1.z, (f16)v1.w};
    *(f16x8*)&Wl[(n << 10) + (k0 ^ ((n & 7) << 3))] = hv;
  }
  for (int ch = tid; ch < (16 * KX / 8); ch += 512) {
    const int n = ch >> (XSH - 3), k0 = (ch & (KX / 8 - 1)) << 3;
    const float* wp = Wih + ((size_t)(dir * 1024 + cg * 16 + n)) * KX + k0;
    float4 v0 = *(const float4*)wp, v1 = *(const float4*)(wp + 4);
    f16x8 hv = {(f16)v0.x, (f16)v0.y, (f16)v0.z, (f16)v0.w,
                (f16)v1.x, (f16)v1.y, (f16)v1.z, (f16)v1.w};
    *(f16x8*)&Wi[(n << XSH) + (k0 ^ ((n & 7) << 3))] = hv;
  }
  const float bn = bsum[(ld << 10) + cg * 16 + (l & 15)];
  f16* hD = hbuf + ((size_t)dir << 17);
  unsigned int* fl = flags + ((dir * 2 + bg) << 10);
  const int arow = bg * 32 + mi * 16 + (l & 15);
  const int akh = (kq << 8) + ((l >> 4) << 3);
  const int akx = kq * (KX / 4) + ((l >> 4) << 3);
  const int wn = l & 15;
  const int wsw = (wn & 7) << 3;

  f16x8 xv[NKX];
  {
    const int t0 = dir ? 511 : 0;
    const f16* xr = X + (((size_t)(t0 * 64 + arow)) << XSH) + akx;
#pragma unroll
    for (int i = 0; i < NKX; i++)
      asm volatile("global_load_dwordx4 %0, %1, off offset:%2"
                   : "=&v"(xv[i]) : "v"(xr), "i"(64 * i));
  }
  __syncthreads();

  for (int s = 0; s < 512; ++s) {
    const int t = dir ? (511 - s) : s;
    f32x4 acc = {0.f, 0.f, 0.f, 0.f};
    if (s > 0) {
      if (w == 7) {
        const unsigned int tgt = (unsigned int)(LAYER * 512 + s);
        unsigned int* fp = fl + l * 16;
        for (;;) {
          unsigned int f = __hip_atomic_load(fp, __ATOMIC_RELAXED, __HIP_MEMORY_SCOPE_AGENT);
          if (__all((int)(f >= tgt))) break;
        }
      }
      __syncthreads();
      const f16* hrow = hD + (((size_t)(s & 1)) << 16) + (((size_t)arow) << 10) + akh;
      f16x8 hv[NKH];
#pragma unroll
      for (int i = 0; i < NKH; i++)
        asm volatile("global_load_dwordx4 %0, %1, off offset:%2 sc0 sc1"
                     : "=&v"(hv[i]) : "v"(hrow), "i"(64 * i));
      asm volatile("s_waitcnt vmcnt(%0)" :: "i"(NKH) : "memory");
      __builtin_amdgcn_sched_barrier(0);
#pragma unroll
      for (int it = 0; it < NKX; ++it) {
        const int ko = akx + it * 32;
        f16x8 bv = *(const f16x8*)&Wi[(wn << XSH) + (ko ^ wsw)];
        acc = __builtin_amdgcn_mfma_f32_16x16x32_f16(xv[it], bv, acc, 0, 0, 0);
      }
      asm volatile("s_waitcnt vmcnt(0)" ::: "memory");
      __builtin_amdgcn_sched_barrier(0);
#pragma unroll
      for (int it = 0; it < NKH; ++it) {
        const int ko = akh + it * 32;
        f16x8 bv = *(const f16x8*)&Wl[(wn << 10) + (ko ^ wsw)];
        acc = __builtin_amdgcn_mfma_f32_16x16x32_f16(hv[it], bv, acc, 0, 0, 0);
      }
    } else {
      asm volatile("s_waitcnt vmcnt(0)" ::: "memory");
      __builtin_amdgcn_sched_barrier(0);
#pragma unroll
      for (int it = 0; it < NKX; ++it) {
        const int ko = akx + it * 32;
        f16x8 bv = *(const f16x8*)&Wi[(wn << XSH) + (ko ^ wsw)];
        acc = __builtin_amdgcn_mfma_f32_16x16x32_f16(xv[it], bv, acc, 0, 0, 0);
      }
    }
    part[mi][kq][l] = acc;
    __syncthreads();
    if (w < 2) {
      f32x4 sum = part[w][0][l];
      sum += part[w][1][l];
      sum += part[w][2][l];
      sum += part[w][3][l];
#pragma unroll
      for (int r = 0; r < 4; ++r) {
        const int row = ((l >> 4) << 2) + r;
        float v = tanh_fast(sum[r] + bn);
        p2[(w << 4) + row][l & 15] = (f16)v;
        if (s == 511) {
          const int b_ = bg * 32 + (w << 4) + row;
          dout[(((size_t)(ld * 64 + b_)) << 10) + cg * 16 + (l & 15)] = v;
        }
      }
      asm volatile("s_waitcnt lgkmcnt(0)" ::: "memory");
      __builtin_amdgcn_sched_barrier(0);
      if (l < 32) {
        const int rr = (w << 4) + (l >> 1), hf = l & 1;
        f16x8 pv = *(const f16x8*)&p2[rr][hf * 8];
        const int b_ = bg * 32 + rr;
        f16* hp = hD + (((size_t)((s + 1) & 1)) << 16) + (((size_t)b_) << 10) + cg * 16 + hf * 8;
        asm volatile("global_store_dwordx4 %0, %1, off sc0 sc1" :: "v"(hp), "v"(pv) : "memory");
        if (LAYER == 0) {
          f16* sp = seqout + (((size_t)(t * 64 + b_)) << 11) + (dir << 10) + cg * 16 + hf * 8;
          asm volatile("global_store_dwordx4 %0, %1, off" :: "v"(sp), "v"(pv) : "memory");
        }
      }
      asm volatile("s_waitcnt vmcnt(0)" ::: "memory");
      __builtin_amdgcn_sched_barrier(0);
      if (l == 0) {
        unsigned int old = __hip_atomic_fetch_add(&cnt, 1u, __ATOMIC_RELAXED,
                                                  __HIP_MEMORY_SCOPE_WORKGROUP);
        if (old == (unsigned int)(2 * s + 1))
          __hip_atomic_store(&fl[cg * 16], (unsigned int)(LAYER * 512 + s + 1),
                             __ATOMIC_RELAXED, __HIP_MEMORY_SCOPE_AGENT);
      }
    }
    if (s + 1 < 512) {
      const int tn_ = dir ? (511 - (s + 1)) : (s + 1);
      const f16* xr = X + (((size_t)(tn_ * 64 + arow)) << XSH) + akx;
#pragma unroll
      for (int i = 0; i < NKX; i++)
        asm volatile("global_load_dwordx4 %0, %1, off offset:%2"
                     : "=&v"(xv[i]) : "v"(xr), "i"(64 * i));
    }
  }
}

// ---------------- PRE recurrence, FULL-K waves (4-wave blocks, single barrier/step) ------------
// w0/w1: compute 16 rows x 16 cols across all K=1024 (32 laddered MFMAs), tanh, store, publish.
// w3: polls 64 padded flags. w2: idle. No cross-wave reduce, no part LDS, one barrier per step.
// LAYER==0: reducers overlay layer-0 output IN PLACE onto the consumed PRE tile.
template <int LAYER>
__global__ __launch_bounds__(256, 1) void rnn_scan_pre(
    f16* __restrict__ PRE0, f16* __restrict__ PRE1,
    const float* __restrict__ Whh, const float* __restrict__ bsum,
    f16* __restrict__ hbuf, unsigned int* __restrict__ flags,  // [4][64][16] u32 padded, zeroed
    float* __restrict__ dout) {
  const int bid = blockIdx.x;
  const int g_ = (bid & 7) >> 1;
  const int dir = g_ >> 1, bg = g_ & 1;
  const int cg = ((bid & 1) << 5) | (bid >> 3);
  const int tid = threadIdx.x, l = tid & 63, w = tid >> 6;
  __shared__ alignas(16) f16 Wl[16 * 1024];
  __shared__ alignas(16) f16 p2[32][16];
  __shared__ unsigned int cnt;
  const int ld = LAYER * 2 + dir;
  if (tid == 0) cnt = 0u;
  for (int ch = tid; ch < 2048; ch += 256) {
    const int n = ch >> 7, k0 = (ch & 127) << 3;
    const float* wp = Whh + (((size_t)(ld * 1024 + cg * 16 + n)) << 10) + k0;
    float4 v0 = *(const float4*)wp, v1 = *(const float4*)(wp + 4);
    f16x8 hv = {(f16)v0.x, (f16)v0.y, (f16)v0.z, (f16)v0.w,
                (f16)v1.x, (f16)v1.y, (f16)v1.z, (f16)v1.w};
    *(f16x8*)&Wl[(n << 10) + (k0 ^ ((n & 7) << 3))] = hv;
  }
  const int pcol = cg * 16 + (l & 15);
  const float bn = bsum[(ld << 10) + pcol];
  f16* preD = dir ? PRE1 : PRE0;
  f16* hD = hbuf + ((size_t)dir << 17);
  unsigned int* fl = flags + ((dir * 2 + bg) << 10);
  const int arow = bg * 32 + (w << 4) + (l & 15);  // compute wave w's batch row (MFMA A)
  const int kb = (l >> 4) << 3;                    // lane k-base (0,8,16,24)
  const int wn = l & 15;
  const int wsw = (wn & 7) << 3;
  const int prow = bg * 32 + (w << 4) + ((l >> 4) << 2);  // pre row base (== C rows of this lane)

  unsigned int pu0 = 0, pu1 = 0, pu2 = 0, pu3 = 0;
  if (w < 2) {  // prologue: asm pre loads for s=0
    const int t0 = dir ? 511 : 0;
    const f16* ppA = preD + (((size_t)(t0 * 64 + prow)) << 10) + pcol;
    const f16* ppB = ppA + 2048;
    asm volatile("global_load_ushort %0, %1, off" : "=&v"(pu0) : "v"(ppA));
    asm volatile("global_load_ushort %0, %1, off offset:2048" : "=&v"(pu1) : "v"(ppA));
    asm volatile("global_load_ushort %0, %1, off" : "=&v"(pu2) : "v"(ppB));
    asm volatile("global_load_ushort %0, %1, off offset:2048" : "=&v"(pu3) : "v"(ppB));
  }
  __syncthreads();

  for (int s = 0; s < 512; ++s) {
    const int t = dir ? (511 - s) : s;
    f32x4 acc = {0.f, 0.f, 0.f, 0.f};
    if (s > 0) {
      if (w == 3) {  // single poller wave
        const unsigned int tgt = (unsigned int)s;
        unsigned int* fp = fl + l * 16;
        for (;;) {
          unsigned int f = __hip_atomic_load(fp, __ATOMIC_RELAXED, __HIP_MEMORY_SCOPE_AGENT);
          if (__all((int)(f >= tgt))) break;
        }
      }
      __syncthreads();
      if (w < 2) {
        // full-K h: 32 laddered LLC loads; ladder overlaps RTT with MFMAs.
        // (older pre loads drain first inside vmcnt(24).)
        const f16* hrow = hD + (((size_t)(s & 1)) << 16) + (((size_t)arow) << 10) + kb;
        f16x8 hv[32];
#pragma unroll
        for (int i = 0; i < 32; i++)
          asm volatile("global_load_dwordx4 %0, %1, off offset:%2 sc0 sc1"
                       : "=&v"(hv[i]) : "v"(hrow), "i"(64 * i));
        asm volatile("s_waitcnt vmcnt(24)" ::: "memory");
        __builtin_amdgcn_sched_barrier(0);
#pragma unroll
        for (int it = 0; it < 8; ++it) {
          const int ko = kb + it * 32;
          f16x8 bv = *(const f16x8*)&Wl[(wn << 10) + (ko ^ wsw)];
          acc = __builtin_amdgcn_mfma_f32_16x16x32_f16(hv[it], bv, acc, 0, 0, 0);
        }
        asm volatile("s_waitcnt vmcnt(16)" ::: "memory");
        __builtin_amdgcn_sched_barrier(0);
#pragma unroll
        for (int it = 8; it < 16; ++it) {
          const int ko = kb + it * 32;
          f16x8 bv = *(const f16x8*)&Wl[(wn << 10) + (ko ^ wsw)];
          acc = __builtin_amdgcn_mfma_f32_16x16x32_f16(hv[it], bv, acc, 0, 0, 0);
        }
        asm volatile("s_waitcnt vmcnt(8)" ::: "memory");
        __builtin_amdgcn_sched_barrier(0);
#pragma unroll
        for (int it = 16; it < 24; ++it) {
          const int ko = kb + it * 32;
          f16x8 bv = *(const f16x8*)&Wl[(wn << 10) + (ko ^ wsw)];
          acc = __builtin_amdgcn_mfma_f32_16x16x32_f16(hv[it], bv, acc, 0, 0, 0);
        }
        asm volatile("s_waitcnt vmcnt(0)" ::: "memory");
        __builtin_amdgcn_sched_barrier(0);
#pragma unroll
        for (int it = 24; it < 32; ++it) {
          const int ko = kb + it * 32;
          f16x8 bv = *(const f16x8*)&Wl[(wn << 10) + (ko ^ wsw)];
          acc = __builtin_amdgcn_mfma_f32_16x16x32_f16(hv[it], bv, acc, 0, 0, 0);
        }
      }
    }
    if (w < 2) {
      asm volatile("s_waitcnt vmcnt(0)" ::: "memory");  // pre regs ready (s=0 prologue case)
      __builtin_amdgcn_sched_barrier(0);
      float pva[4];
      pva[0] = (float)__builtin_bit_cast(f16, (unsigned short)pu0);
      pva[1] = (float)__builtin_bit_cast(f16, (unsigned short)pu1);
      pva[2] = (float)__builtin_bit_cast(f16, (unsigned short)pu2);
      pva[3] = (float)__builtin_bit_cast(f16, (unsigned short)pu3);
#pragma unroll
      for (int r = 0; r < 4; ++r) {
        const int row = ((l >> 4) << 2) + r;
        float v = tanh_fast(acc[r] + pva[r] + bn);
        p2[(w << 4) + row][l & 15] = (f16)v;
        if (s == 511) {
          const int b_ = bg * 32 + (w << 4) + row;
          dout[(((size_t)(ld * 64 + b_)) << 10) + pcol] = v;
        }
      }
      asm volatile("s_waitcnt lgkmcnt(0)" ::: "memory");  // p2 (own-wave rows) visible
      __builtin_amdgcn_sched_barrier(0);
      if (l < 32) {
        const int rr = (w << 4) + (l >> 1), hf = l & 1;
        f16x8 pv = *(const f16x8*)&p2[rr][hf * 8];
        const int b_ = bg * 32 + rr;
        f16* hp = hD + (((size_t)((s + 1) & 1)) << 16) + (((size_t)b_) << 10) + cg * 16 + hf * 8;
        asm volatile("global_store_dwordx4 %0, %1, off sc0 sc1" :: "v"(hp), "v"(pv) : "memory");
        if (LAYER == 0) {  // in-place overlay: layer-0 output over the consumed pre tile
          f16* xp = preD + (((size_t)(t * 64 + b_)) << 10) + cg * 16 + hf * 8;
          asm volatile("global_store_dwordx4 %0, %1, off" :: "v"(xp), "v"(pv) : "memory");
        }
      }
      asm volatile("s_waitcnt vmcnt(0)" ::: "memory");  // h stores visible at LLC
      __builtin_amdgcn_sched_barrier(0);
      if (l == 0) {  // last-man of the two compute waves publishes
        unsigned int old = __hip_atomic_fetch_add(&cnt, 1u, __ATOMIC_RELAXED,
                                                  __HIP_MEMORY_SCOPE_WORKGROUP);
        if (old == (unsigned int)(2 * s + 1))
          __hip_atomic_store(&fl[cg * 16], (unsigned int)(s + 1),
                             __ATOMIC_RELAXED, __HIP_MEMORY_SCOPE_AGENT);
      }
      if (s + 1 < 512) {  // single asm issue site, after publish
        const int tn_ = dir ? (511 - (s + 1)) : (s + 1);
        const f16* ppA = preD + (((size_t)(tn_ * 64 + prow)) << 10) + pcol;
        const f16* ppB = ppA + 2048;
        asm volatile("global_load_ushort %0, %1, off" : "=&v"(pu0) : "v"(ppA));
        asm volatile("global_load_ushort %0, %1, off offset:2048" : "=&v"(pu1) : "v"(ppA));
        asm volatile("global_load_ushort %0, %1, off" : "=&v"(pu2) : "v"(ppB));
        asm volatile("global_load_ushort %0, %1, off offset:2048" : "=&v"(pu3) : "v"(ppB));
      }
    }
  }
}

// ---------------- launch ----------------

extern "C" void kernel_launch(void* const* d_in, const int* in_sizes, int n_in,
                              void* d_out, int out_size, void* d_ws, size_t ws_size,
                              hipStream_t stream) {
  const int* src    = (const int*)d_in[0];
  const float* emb  = (const float*)d_in[1];
  const float* W1   = (const float*)d_in[2];
  const float* b1   = (const float*)d_in[3];
  const float* W2   = (const float*)d_in[4];
  const float* b2   = (const float*)d_in[5];
  const float* Wih0 = (const float*)d_in[6];
  const float* WihL = (const float*)d_in[7];
  const float* Whh  = (const float*)d_in[8];
  const float* bih  = (const float*)d_in[9];
  const float* bhh  = (const float*)d_in[10];
  float* out = (float*)d_out;
  char* ws = (char*)d_ws;

  if (ws_size < WS_NEED) {  // diagnostic fallback
    zero_k<<<(out_size + 255) / 256, 256, 0, stream>>>((unsigned int*)d_out, out_size);
    return;
  }

  if (ws_size >= WS_NEED2) {
    // ================= all-PRE path (256MB) =================
    f16* X0    = (f16*)(ws + Q_X0);
    f16* EMB   = (f16*)(ws + Q_EMB);
    f16* MLP1  = (f16*)(ws + Q_MLP1);
    f16* W1C   = (f16*)(ws + Q_W1C);
    f16* W2C   = (f16*)(ws + Q_W2C);
    f16* PRE0D0 = (f16*)(ws + Q_PRE0D0);
    f16* PRE0D1 = (f16*)(ws + Q_PRE0D1);
    f16* HB0   = (f16*)(ws + Q_HB0);
    unsigned int* FL0 = (unsigned int*)(ws + Q_FL0);
    float* BIAS0 = (float*)(ws + Q_BIAS0);
    f16* PRE1D0 = (f16*)(ws + Q_PRE1D0);
    f16* PRE1D1 = (f16*)(ws + Q_PRE1D1);
    f16* HB1   = (f16*)(ws + Q_HB1);
    unsigned int* FL1 = (unsigned int*)(ws + Q_FL1);
    float* BIAS1 = (float*)(ws + Q_BIAS1);

    cvt_k<<<256, 256, 0, stream>>>(W1, W1C, 131072);
    cvt_k<<<256, 256, 0, stream>>>(W2, W2C, 262144);

    embed_k<<<32768, 128, 0, stream>>>(src, emb, EMB);
    gemm_f16<1><<<2048, 256, 0, stream>>>(EMB, 512, W1C, MLP1, b1, 32768, 1024, 512);
    gemm_f16<3><<<2048, 256, 0, stream>>>(MLP1, 1024, W2C, X0, b2, 32768, 1024, 1024);

    gemm_b32<<<2048, 256, 0, stream>>>(X0, 1024, Wih0, PRE0D0, 32768, 1024, 1024);
    gemm_b32<<<2048, 256, 0, stream>>>(X0, 1024, Wih0 + (1u << 20), PRE0D1, 32768, 1024, 1024);
    zero_k<<<16, 256, 0, stream>>>(FL0, 4096);
    bias_k<<<16, 256, 0, stream>>>(bih, bhh, BIAS0);
    rnn_scan_pre<0><<<256, 256, 0, stream>>>(PRE0D0, PRE0D1, Whh, BIAS0, HB0, FL0, out);

    gemm_b32c<<<2048, 256, 0, stream>>>(PRE0D0, PRE0D1, WihL, PRE1D0, 32768, 1024);
    gemm_b32c<<<2048, 256, 0, stream>>>(PRE0D0, PRE0D1, WihL + (1u << 21), PRE1D1, 32768, 1024);
    zero_k<<<16, 256, 0, stream>>>(FL1, 4096);
    bias_k<<<16, 256, 0, stream>>>(bih, bhh, BIAS1);
    rnn_scan_pre<1><<<256, 256, 0, stream>>>(PRE1D0, PRE1D1, Whh, BIAS1, HB1, FL1, out);
    return;
  }

  // ================= fused fallback (R14, 196MB) =================
  f16* X0   = (f16*)(ws + OFF_X0);
  f16* X1   = (f16*)(ws + OFF_X1);
  f16* EMB  = (f16*)(ws + OFF_EMB);
  f16* MLP1 = (f16*)(ws + OFF_MLP1);
  f16* HB   = (f16*)(ws + OFF_H);
  unsigned int* FLAGS = (unsigned int*)(ws + OFF_FLAGS);
  float* BIAS = (float*)(ws + OFF_BIAS);
  f16* W1C  = (f16*)(ws + OFF_W1C);
  f16* W2C  = (f16*)(ws + OFF_W2C);

  cvt_k<<<256, 256, 0, stream>>>(W1, W1C, 131072);
  cvt_k<<<256, 256, 0, stream>>>(W2, W2C, 262144);
  bias_k<<<16, 256, 0, stream>>>(bih, bhh, BIAS);
  zero_k<<<16, 256, 0, stream>>>(FLAGS, 4096);

  embed_k<<<32768, 128, 0, stream>>>(src, emb, EMB);
  gemm_f16<1><<<2048, 256, 0, stream>>>(EMB, 512, W1C, MLP1, b1, 32768, 1024, 512);
  gemm_f16<3><<<2048, 256, 0, stream>>>(MLP1, 1024, W2C, X0, b2, 32768, 1024, 1024);

  rnn_scan<0><<<256, 512, 0, stream>>>(X0, Wih0, Whh, BIAS, HB, FLAGS, X1, out);
  rnn_scan<1><<<256, 512, 0, stream>>>(X1, WihL, Whh, BIAS, HB, FLAGS, nullptr, out);
}